// Round 17
// baseline (1224.703 us; speedup 1.0000x reference)
//
#include <hip/hip_runtime.h>
#include <math.h>

// Problem constants
#define BB 4
#define SS 1024
#define DD 2048
#define HH 16
#define DKK 128
#define KKTOP 307           // int(1024 * 0.3)
#define MROWS (BB * SS)     // 4096
#define KPLANE ((size_t)MROWS * DD)   // elements per K-split plane (8,388,608)
static __device__ __constant__ float SCALE = 0.08838834764831845f; // 1/sqrt(128)

typedef float f32x4 __attribute__((ext_vector_type(4)));
typedef unsigned short su4 __attribute__((ext_vector_type(4)));
typedef unsigned short su8 __attribute__((ext_vector_type(8)));

__device__ __forceinline__ unsigned short f2bf(float x) {   // RNE
    unsigned u = __float_as_uint(x);
    u += 0x7fffu + ((u >> 16) & 1u);
    return (unsigned short)(u >> 16);
}
__device__ __forceinline__ float bf2f(unsigned short b) {
    return __uint_as_float((unsigned)b << 16);
}
__device__ __forceinline__ unsigned f2u_ord(float f) {
    unsigned x = __float_as_uint(f);
    return (x & 0x80000000u) ? ~x : (x | 0x80000000u);
}
__device__ __forceinline__ float u2f_ord(unsigned u) {
    return __uint_as_float((u & 0x80000000u) ? (u & 0x7fffffffu) : ~u);
}
// 3-way bf16 split of fp32 (captures ~24 mantissa bits)
__device__ __forceinline__ void split4(float4 v, su4& a, su4& b, su4& c) {
    float x[4] = {v.x, v.y, v.z, v.w};
    #pragma unroll
    for (int i = 0; i < 4; ++i) {
        unsigned short b1 = f2bf(x[i]);
        float r = x[i] - bf2f(b1);
        unsigned short b2 = f2bf(r);
        float r2 = r - bf2f(b2);
        a[i] = b1; b[i] = b2; c[i] = f2bf(r2);
    }
}
// 2-way bf16 split of fp32 (residual <= 2^-9 |x|)
__device__ __forceinline__ void split2_4(float4 v, su4& a, su4& b) {
    float x[4] = {v.x, v.y, v.z, v.w};
    #pragma unroll
    for (int i = 0; i < 4; ++i) {
        unsigned short b1 = f2bf(x[i]);
        float r = x[i] - bf2f(b1);
        a[i] = b1; b[i] = f2bf(r);
    }
}
__device__ __forceinline__ su8 cat44(su4 a, su4 b) {
    su8 r;
    r[0] = a[0]; r[1] = a[1]; r[2] = a[2]; r[3] = a[3];
    r[4] = b[0]; r[5] = b[1]; r[6] = b[2]; r[7] = b[3];
    return r;
}

#define TM 128
#define TN 128

// ---------------------------------------------------------------------------
// GEMM 3-pass split-bf16 MFMA (round-12 verified, verbatim). Used for Q.
// ---------------------------------------------------------------------------
#define G3LD 40

__global__ __launch_bounds__(256) void gemm_nt_3p(
    const float* __restrict__ A, const float* __restrict__ W,
    const float* __restrict__ bias, float* __restrict__ C,
    int M, int N, int K)
{
    __shared__ unsigned short A1[128][G3LD];
    __shared__ unsigned short A2[128][G3LD];
    __shared__ unsigned short B1[128][G3LD];
    __shared__ unsigned short B2[128][G3LD];

    const int tid = threadIdx.x;
    const int bm = blockIdx.x * 128;
    const int bn = blockIdx.y * 128;
    const int wm = (tid >> 6) & 1;
    const int wn = tid >> 7;
    const int lane = tid & 63;
    const int lrow = tid >> 1;
    const int lcol = (tid & 1) * 16;

    f32x4 acc[4][4];
    #pragma unroll
    for (int i = 0; i < 4; ++i)
        #pragma unroll
        for (int j = 0; j < 4; ++j)
            acc[i][j] = (f32x4){0.f, 0.f, 0.f, 0.f};

    for (int kt = 0; kt < K; kt += 32) {
        __syncthreads();
        {
            const float* Ag = A + (size_t)(bm + lrow) * K + kt + lcol;
            const float* Wg = W + (size_t)(bn + lrow) * K + kt + lcol;
            float4 v0, v1; su4 h0, l0, h1, l1;
            v0 = *(const float4*)(Ag + 0);  v1 = *(const float4*)(Ag + 4);
            split2_4(v0, h0, l0); split2_4(v1, h1, l1);
            *(su8*)&A1[lrow][lcol + 0] = cat44(h0, h1);
            *(su8*)&A2[lrow][lcol + 0] = cat44(l0, l1);
            v0 = *(const float4*)(Ag + 8);  v1 = *(const float4*)(Ag + 12);
            split2_4(v0, h0, l0); split2_4(v1, h1, l1);
            *(su8*)&A1[lrow][lcol + 8] = cat44(h0, h1);
            *(su8*)&A2[lrow][lcol + 8] = cat44(l0, l1);
            v0 = *(const float4*)(Wg + 0);  v1 = *(const float4*)(Wg + 4);
            split2_4(v0, h0, l0); split2_4(v1, h1, l1);
            *(su8*)&B1[lrow][lcol + 0] = cat44(h0, h1);
            *(su8*)&B2[lrow][lcol + 0] = cat44(l0, l1);
            v0 = *(const float4*)(Wg + 8);  v1 = *(const float4*)(Wg + 12);
            split2_4(v0, h0, l0); split2_4(v1, h1, l1);
            *(su8*)&B1[lrow][lcol + 8] = cat44(h0, h1);
            *(su8*)&B2[lrow][lcol + 8] = cat44(l0, l1);
        }
        __syncthreads();

        su8 a1[4], a2[4], b1[4], b2[4];
        #pragma unroll
        for (int f = 0; f < 4; ++f) {
            const int fr = f * 16 + (lane & 15);
            const int fk = (lane >> 4) * 8;
            a1[f] = *(const su8*)&A1[wm * 64 + fr][fk];
            a2[f] = *(const su8*)&A2[wm * 64 + fr][fk];
            b1[f] = *(const su8*)&B1[wn * 64 + fr][fk];
            b2[f] = *(const su8*)&B2[wn * 64 + fr][fk];
        }
        #pragma unroll
        for (int fi = 0; fi < 4; ++fi)
            #pragma unroll
            for (int fj = 0; fj < 4; ++fj) {
                asm volatile("v_mfma_f32_16x16x32_bf16 %0, %1, %2, %0"
                             : "+v"(acc[fi][fj]) : "v"(a1[fi]), "v"(b2[fj]));
                asm volatile("v_mfma_f32_16x16x32_bf16 %0, %1, %2, %0"
                             : "+v"(acc[fi][fj]) : "v"(a2[fi]), "v"(b1[fj]));
                asm volatile("v_mfma_f32_16x16x32_bf16 %0, %1, %2, %0"
                             : "+v"(acc[fi][fj]) : "v"(a1[fi]), "v"(b1[fj]));
            }
    }

    asm volatile("s_nop 7\n\ts_nop 7" ::: "memory");

    #pragma unroll
    for (int fj = 0; fj < 4; ++fj) {
        const int col = bn + wn * 64 + fj * 16 + (lane & 15);
        const float bv = bias[col];
        #pragma unroll
        for (int fi = 0; fi < 4; ++fi) {
            const int r0 = bm + wm * 64 + fi * 16 + (lane >> 4) * 4;
            #pragma unroll
            for (int j = 0; j < 4; ++j)
                C[(size_t)(r0 + j) * N + col] = acc[fi][fj][j] + bv;
        }
    }
}

// ---------------------------------------------------------------------------
// Same 3-pass core, K-split epilogue (round-12 verified, verbatim).
// ---------------------------------------------------------------------------
__global__ __launch_bounds__(256) void gemm_nt_3p_ksplit(
    const float* __restrict__ A, const float* __restrict__ W,
    const float* __restrict__ bias, unsigned short* __restrict__ Ks,
    int M, int N, int K)
{
    __shared__ unsigned short A1[128][G3LD];
    __shared__ unsigned short A2[128][G3LD];
    __shared__ unsigned short B1[128][G3LD];
    __shared__ unsigned short B2[128][G3LD];

    const int tid = threadIdx.x;
    const int bm = blockIdx.x * 128;
    const int bn = blockIdx.y * 128;
    const int wm = (tid >> 6) & 1;
    const int wn = tid >> 7;
    const int lane = tid & 63;
    const int lrow = tid >> 1;
    const int lcol = (tid & 1) * 16;

    f32x4 acc[4][4];
    #pragma unroll
    for (int i = 0; i < 4; ++i)
        #pragma unroll
        for (int j = 0; j < 4; ++j)
            acc[i][j] = (f32x4){0.f, 0.f, 0.f, 0.f};

    for (int kt = 0; kt < K; kt += 32) {
        __syncthreads();
        {
            const float* Ag = A + (size_t)(bm + lrow) * K + kt + lcol;
            const float* Wg = W + (size_t)(bn + lrow) * K + kt + lcol;
            float4 v0, v1; su4 h0, l0, h1, l1;
            v0 = *(const float4*)(Ag + 0);  v1 = *(const float4*)(Ag + 4);
            split2_4(v0, h0, l0); split2_4(v1, h1, l1);
            *(su8*)&A1[lrow][lcol + 0] = cat44(h0, h1);
            *(su8*)&A2[lrow][lcol + 0] = cat44(l0, l1);
            v0 = *(const float4*)(Ag + 8);  v1 = *(const float4*)(Ag + 12);
            split2_4(v0, h0, l0); split2_4(v1, h1, l1);
            *(su8*)&A1[lrow][lcol + 8] = cat44(h0, h1);
            *(su8*)&A2[lrow][lcol + 8] = cat44(l0, l1);
            v0 = *(const float4*)(Wg + 0);  v1 = *(const float4*)(Wg + 4);
            split2_4(v0, h0, l0); split2_4(v1, h1, l1);
            *(su8*)&B1[lrow][lcol + 0] = cat44(h0, h1);
            *(su8*)&B2[lrow][lcol + 0] = cat44(l0, l1);
            v0 = *(const float4*)(Wg + 8);  v1 = *(const float4*)(Wg + 12);
            split2_4(v0, h0, l0); split2_4(v1, h1, l1);
            *(su8*)&B1[lrow][lcol + 8] = cat44(h0, h1);
            *(su8*)&B2[lrow][lcol + 8] = cat44(l0, l1);
        }
        __syncthreads();

        su8 a1[4], a2[4], b1[4], b2[4];
        #pragma unroll
        for (int f = 0; f < 4; ++f) {
            const int fr = f * 16 + (lane & 15);
            const int fk = (lane >> 4) * 8;
            a1[f] = *(const su8*)&A1[wm * 64 + fr][fk];
            a2[f] = *(const su8*)&A2[wm * 64 + fr][fk];
            b1[f] = *(const su8*)&B1[wn * 64 + fr][fk];
            b2[f] = *(const su8*)&B2[wn * 64 + fr][fk];
        }
        #pragma unroll
        for (int fi = 0; fi < 4; ++fi)
            #pragma unroll
            for (int fj = 0; fj < 4; ++fj) {
                asm volatile("v_mfma_f32_16x16x32_bf16 %0, %1, %2, %0"
                             : "+v"(acc[fi][fj]) : "v"(a1[fi]), "v"(b2[fj]));
                asm volatile("v_mfma_f32_16x16x32_bf16 %0, %1, %2, %0"
                             : "+v"(acc[fi][fj]) : "v"(a2[fi]), "v"(b1[fj]));
                asm volatile("v_mfma_f32_16x16x32_bf16 %0, %1, %2, %0"
                             : "+v"(acc[fi][fj]) : "v"(a1[fi]), "v"(b1[fj]));
            }
    }

    asm volatile("s_nop 7\n\ts_nop 7" ::: "memory");

    #pragma unroll
    for (int fj = 0; fj < 4; ++fj) {
        const int col = bn + wn * 64 + fj * 16 + (lane & 15);
        const int h = col >> 7, d = col & (DKK - 1);
        const float bv = bias[col];
        #pragma unroll
        for (int fi = 0; fi < 4; ++fi) {
            const int r0 = bm + wm * 64 + fi * 16 + (lane >> 4) * 4;
            #pragma unroll
            for (int j = 0; j < 4; ++j) {
                const int tok = r0 + j;
                const float val = acc[fi][fj][j] + bv;
                const size_t o = ((size_t)((tok >> 10) * HH + h) * SS
                                  + (tok & (SS - 1))) * DKK + d;
                unsigned short s1 = f2bf(val);
                float r = val - bf2f(s1);
                unsigned short s2 = f2bf(r);
                float r2 = r - bf2f(s2);
                Ks[0 * KPLANE + o] = s1;
                Ks[1 * KPLANE + o] = s2;
                Ks[2 * KPLANE + o] = f2bf(r2);
            }
        }
    }
}

// ---------------------------------------------------------------------------
// GEMM bf16-MFMA (round-6 verified, verbatim): fp32 in/out. Used for O-proj.
// ---------------------------------------------------------------------------
#define GLDA 40

__device__ __forceinline__ su8 pack8(float4 x, float4 y) {
    su8 r;
    r[0] = f2bf(x.x); r[1] = f2bf(x.y); r[2] = f2bf(x.z); r[3] = f2bf(x.w);
    r[4] = f2bf(y.x); r[5] = f2bf(y.y); r[6] = f2bf(y.z); r[7] = f2bf(y.w);
    return r;
}

__global__ __launch_bounds__(256) void gemm_nt_bf16(
    const float* __restrict__ A, const float* __restrict__ W,
    const float* __restrict__ bias, float* __restrict__ C,
    int M, int N, int K)
{
    __shared__ unsigned short Ab[128][GLDA];
    __shared__ unsigned short Bb[128][GLDA];

    const int tid = threadIdx.x;
    const int bm = blockIdx.x * 128;
    const int bn = blockIdx.y * 128;
    const int wm = (tid >> 6) & 1;
    const int wn = tid >> 7;
    const int lane = tid & 63;
    const int lrow = tid >> 1;
    const int lcol = (tid & 1) * 16;

    f32x4 acc[4][4];
    #pragma unroll
    for (int i = 0; i < 4; ++i)
        #pragma unroll
        for (int j = 0; j < 4; ++j)
            acc[i][j] = (f32x4){0.f, 0.f, 0.f, 0.f};

    for (int kt = 0; kt < K; kt += 32) {
        __syncthreads();
        {
            const float* Ag = A + (size_t)(bm + lrow) * K + kt + lcol;
            const float* Wg = W + (size_t)(bn + lrow) * K + kt + lcol;
            float4 a0 = *(const float4*)(Ag + 0);
            float4 a1 = *(const float4*)(Ag + 4);
            float4 a2 = *(const float4*)(Ag + 8);
            float4 a3 = *(const float4*)(Ag + 12);
            *(su8*)&Ab[lrow][lcol + 0] = pack8(a0, a1);
            *(su8*)&Ab[lrow][lcol + 8] = pack8(a2, a3);
            float4 b0 = *(const float4*)(Wg + 0);
            float4 b1 = *(const float4*)(Wg + 4);
            float4 b2 = *(const float4*)(Wg + 8);
            float4 b3 = *(const float4*)(Wg + 12);
            *(su8*)&Bb[lrow][lcol + 0] = pack8(b0, b1);
            *(su8*)&Bb[lrow][lcol + 8] = pack8(b2, b3);
        }
        __syncthreads();

        su8 af[4], bf[4];
        #pragma unroll
        for (int f = 0; f < 4; ++f) {
            af[f] = *(const su8*)&Ab[wm * 64 + f * 16 + (lane & 15)][(lane >> 4) * 8];
            bf[f] = *(const su8*)&Bb[wn * 64 + f * 16 + (lane & 15)][(lane >> 4) * 8];
        }
        #pragma unroll
        for (int fi = 0; fi < 4; ++fi)
            #pragma unroll
            for (int fj = 0; fj < 4; ++fj)
                asm volatile("v_mfma_f32_16x16x32_bf16 %0, %1, %2, %0"
                             : "+v"(acc[fi][fj])
                             : "v"(af[fi]), "v"(bf[fj]));
    }

    asm volatile("s_nop 7\n\ts_nop 7" ::: "memory");

    #pragma unroll
    for (int fj = 0; fj < 4; ++fj) {
        const int col = bn + wn * 64 + fj * 16 + (lane & 15);
        const float bv = bias[col];
        #pragma unroll
        for (int fi = 0; fi < 4; ++fi) {
            const int r0 = bm + wm * 64 + fi * 16 + (lane >> 4) * 4;
            #pragma unroll
            for (int j = 0; j < 4; ++j)
                C[(size_t)(r0 + j) * N + col] = acc[fi][fj][j] + bv;
        }
    }
}

// ---------------------------------------------------------------------------
// GEMM bf16-MFMA, transposed-V variant (round-8 verified, verbatim).
// ---------------------------------------------------------------------------
__global__ __launch_bounds__(256) void gemm_nt_bf16_tv(
    const float* __restrict__ A, const float* __restrict__ W,
    const float* __restrict__ bias, unsigned short* __restrict__ Cb,
    int M, int N, int K)
{
    __shared__ unsigned short Ab[128][GLDA];
    __shared__ unsigned short Bb[128][GLDA];

    const int tid = threadIdx.x;
    const int bm = blockIdx.x * 128;
    const int bn = blockIdx.y * 128;
    const int wm = (tid >> 6) & 1;
    const int wn = tid >> 7;
    const int lane = tid & 63;
    const int lrow = tid >> 1;
    const int lcol = (tid & 1) * 16;

    f32x4 acc[4][4];
    #pragma unroll
    for (int i = 0; i < 4; ++i)
        #pragma unroll
        for (int j = 0; j < 4; ++j)
            acc[i][j] = (f32x4){0.f, 0.f, 0.f, 0.f};

    for (int kt = 0; kt < K; kt += 32) {
        __syncthreads();
        {
            const float* Ag = A + (size_t)(bm + lrow) * K + kt + lcol;
            const float* Wg = W + (size_t)(bn + lrow) * K + kt + lcol;
            float4 a0 = *(const float4*)(Ag + 0);
            float4 a1 = *(const float4*)(Ag + 4);
            float4 a2 = *(const float4*)(Ag + 8);
            float4 a3 = *(const float4*)(Ag + 12);
            *(su8*)&Ab[lrow][lcol + 0] = pack8(a0, a1);
            *(su8*)&Ab[lrow][lcol + 8] = pack8(a2, a3);
            float4 b0 = *(const float4*)(Wg + 0);
            float4 b1 = *(const float4*)(Wg + 4);
            float4 b2 = *(const float4*)(Wg + 8);
            float4 b3 = *(const float4*)(Wg + 12);
            *(su8*)&Bb[lrow][lcol + 0] = pack8(b0, b1);
            *(su8*)&Bb[lrow][lcol + 8] = pack8(b2, b3);
        }
        __syncthreads();

        su8 af[4], bf[4];
        #pragma unroll
        for (int f = 0; f < 4; ++f) {
            af[f] = *(const su8*)&Ab[wm * 64 + f * 16 + (lane & 15)][(lane >> 4) * 8];
            bf[f] = *(const su8*)&Bb[wn * 64 + f * 16 + (lane & 15)][(lane >> 4) * 8];
        }
        #pragma unroll
        for (int fi = 0; fi < 4; ++fi)
            #pragma unroll
            for (int fj = 0; fj < 4; ++fj)
                asm volatile("v_mfma_f32_16x16x32_bf16 %0, %1, %2, %0"
                             : "+v"(acc[fi][fj])
                             : "v"(af[fi]), "v"(bf[fj]));
    }

    asm volatile("s_nop 7\n\ts_nop 7" ::: "memory");

    #pragma unroll
    for (int fj = 0; fj < 4; ++fj) {
        const int col = bn + wn * 64 + fj * 16 + (lane & 15);
        #pragma unroll
        for (int fi = 0; fi < 4; ++fi) {
            const int r0 = bm + wm * 64 + fi * 16 + (lane >> 4) * 4;
            #pragma unroll
            for (int j = 0; j < 4; ++j) {
                float v = acc[fi][fj][j] + bias[r0 + j];
                Cb[(size_t)(r0 + j) * N + col] = f2bf(v);
            }
        }
    }
}

// ---------------------------------------------------------------------------
// Fused attn — round-13/16 anchor + ONE mechanism: k_s stride 136 -> 140 su
// (272 B = 4 banks mod 32 caused ~8-way b128 read conflicts; 280 B = 6 mod 32
// spreads 16 fc-rows over 16 distinct bank-group starts -> ~2-way free).
// To fit under 64 KB static LDS: q_s dropped, af Q-frags computed per-lane
// from global (r15-correctness-proven component; Q read once/block, 32B
// granules fully used). red gets standalone 4 KB slot. All staged VALUES and
// arithmetic bit-identical -> absmax must stay 2.685547e-3.
// Carve: scores: red 4KB @0 | k_s 3x[64][140] @4096 (ends 57856)
//        PV:     wt [16][1032] @0 | vt [128][72] @33024 (ends 51456)
// ---------------------------------------------------------------------------
#define ATT_LDS 57856
#define KLD 140            // k_s row stride in su (280 B == 6 banks mod 32)
#define KPL (64 * KLD)     // su per k_s plane (8960)

__global__ __launch_bounds__(512) void attn_topk_fused(
    const float* __restrict__ Qb, const unsigned short* __restrict__ Ks,
    const unsigned short* __restrict__ Vt, float* __restrict__ attn_out,
    float* __restrict__ CTX)
{
    __shared__ __align__(16) char smem[ATT_LDS];
    float*          red = (float*)smem;                    // [4][16][16] (scores)
    unsigned short* k_s = (unsigned short*)(smem + 4096);  // [3][64][140] (scores)
    unsigned short* wt  = (unsigned short*)smem;           // [16][1032]   (PV)
    unsigned short* vt  = (unsigned short*)(smem + 33024); // [128][72]    (PV)

    const int tid = threadIdx.x;
    const int wv = tid >> 6, lane = tid & 63;
    const int fg = lane >> 4, fc = lane & 15;

    // XCD-chunked bijective remap: 4096 = 8 XCDs x 512
    const int gg = (blockIdx.x & 7) * 512 + ((int)blockIdx.x >> 3);
    const int bh = gg >> 6, qb = gg & 63;
    const int b = bh >> 4, h = bh & 15;
    const int q0 = qb * 16;

    const float* Qg = Qb + (size_t)(b * SS + q0) * DD + h * DKK;
    const unsigned short* Ksg = Ks + (size_t)bh * SS * DKK;
    const unsigned short* Vtg = Vt + (size_t)(h * DKK) * MROWS + b * SS;
    float* aob = attn_out + (size_t)(bh * SS + q0) * SS;

    const int kt0 = (wv >> 2) * 2;   // ktile base: 0 (d 0..63) or 2 (d 64..127)

    // ---- issue K tile-0 prefetch (3 planes, coalesced) ----
    su8 rk[6];
    #pragma unroll
    for (int pu = 0; pu < 6; ++pu) {
        const int p = pu >> 1;
        const int rem = tid + 512 * (pu & 1);
        const int row = rem >> 4, c8 = rem & 15;
        rk[pu] = *(const su8*)(Ksg + p * KPLANE +
                               (size_t)row * DKK + c8 * 8);
    }

    // ---- per-lane A-frags from global (r15-proven: identical split4 bits) ----
    su8 af[3][2];
    #pragma unroll
    for (int kk = 0; kk < 2; ++kk) {
        const int d0 = ((kt0 + kk) * 4 + fg) * 8;
        float4 f0 = *(const float4*)(Qg + (size_t)fc * DD + d0);
        float4 f1 = *(const float4*)(Qg + (size_t)fc * DD + d0 + 4);
        su4 a1, a2, a3, b1, b2, b3;
        split4(f0, a1, a2, a3);
        split4(f1, b1, b2, b3);
        af[0][kk] = cat44(a1, b1);
        af[1][kk] = cat44(a2, b2);
        af[2][kk] = cat44(a3, b3);
    }

    // ---- scores over 16 key-tiles of 64 (prefetched pipeline) ----
    unsigned uv[2][16];
    for (int t = 0; t < 16; ++t) {
        // write prefetched tile t (k_s reads of t-1 done before barrier-2(t-1);
        // t=0 has no prior readers)
        #pragma unroll
        for (int pu = 0; pu < 6; ++pu) {
            const int p = pu >> 1;
            const int rem = tid + 512 * (pu & 1);
            const int row = rem >> 4, c8 = rem & 15;
            *(su8*)&k_s[p * KPL + row * KLD + c8 * 8] = rk[pu];
        }
        // issue loads for tile t+1 (fly during MFMA + barriers)
        if (t < 15) {
            #pragma unroll
            for (int pu = 0; pu < 6; ++pu) {
                const int p = pu >> 1;
                const int rem = tid + 512 * (pu & 1);
                const int row = rem >> 4, c8 = rem & 15;
                rk[pu] = *(const su8*)(Ksg + p * KPLANE +
                            (size_t)((t + 1) * 64 + row) * DKK + c8 * 8);
            }
        }
        __syncthreads();   // barrier-1: k_s tile t visible

        const int krow = (wv & 3) * 16 + fc;
        su8 bf[3][2];
        #pragma unroll
        for (int p = 0; p < 3; ++p)
            #pragma unroll
            for (int kk = 0; kk < 2; ++kk)
                bf[p][kk] = *(const su8*)&k_s[p * KPL + krow * KLD +
                                ((kt0 + kk) * 4 + fg) * 8];

        f32x4 acc = {0.f, 0.f, 0.f, 0.f};
        // passes small->large: (q3,k1),(q1,k3),(q2,k2),(q2,k1),(q1,k2),(q1,k1)
        constexpr int PI[6] = {2, 0, 1, 1, 0, 0};
        constexpr int PJ[6] = {0, 2, 1, 0, 1, 0};
        #pragma unroll
        for (int p = 0; p < 6; ++p)
            #pragma unroll
            for (int kk = 0; kk < 2; ++kk)
                asm volatile("v_mfma_f32_16x16x32_bf16 %0, %1, %2, %0"
                             : "+v"(acc) : "v"(af[PI[p]][kk]), "v"(bf[PJ[p]][kk]));
        asm volatile("s_nop 7\n\ts_nop 7" ::: "memory");

        if (kt0 == 2) {
            #pragma unroll
            for (int j = 0; j < 4; ++j)
                red[(wv & 3) * 256 + (4 * fg + j) * 16 + fc] = acc[j];
        }
        __syncthreads();   // barrier-2: red visible; k_s reads done
        if (kt0 == 0) {
            #pragma unroll
            for (int j = 0; j < 4; ++j) {
                float s = (acc[j] + red[(wv & 3) * 256 + (4 * fg + j) * 16 + fc]) * SCALE;
                aob[(size_t)(4 * fg + j) * SS + t * 64 + (wv & 3) * 16 + fc] = s;
            }
        }
    }
    __syncthreads();  // scores visible; red reads done (wt overlay safe)

    // ---- selection + softmax params (verified ballot bit-descent), 2 rows ----
    #pragma unroll
    for (int rr = 0; rr < 2; ++rr) {
        const float* aor = aob + (size_t)(2 * wv + rr) * SS;
        #pragma unroll
        for (int t = 0; t < 16; ++t)
            uv[rr][t] = f2u_ord(aor[t * 64 + lane]);
    }
    unsigned pref[2]; int ecnt[2]; float mrow[2], invz[2], tvexp[2];
    #pragma unroll
    for (int rr = 0; rr < 2; ++rr) {
        unsigned p = 0;
        for (int bit = 31; bit >= 0; --bit) {
            unsigned cand = p | (1u << bit);
            int cnt = 0;
            #pragma unroll
            for (int t = 0; t < 16; ++t)
                cnt += __popcll(__ballot(uv[rr][t] >= cand));
            if (cnt >= KKTOP) p = cand;
        }
        pref[rr] = p;
        int g = 0;
        #pragma unroll
        for (int t = 0; t < 16; ++t)
            g += __popcll(__ballot(uv[rr][t] > p));
        ecnt[rr] = KKTOP - g;

        unsigned um = 0;
        #pragma unroll
        for (int t = 0; t < 16; ++t) um = um > uv[rr][t] ? um : uv[rr][t];
        #pragma unroll
        for (int o = 32; o > 0; o >>= 1) {
            unsigned tv2 = __shfl_down(um, o);
            um = um > tv2 ? um : tv2;
        }
        um = __shfl(um, 0);
        const float m = u2f_ord(um);

        float se = 0.f;
        #pragma unroll
        for (int t = 0; t < 16; ++t)
            if (uv[rr][t] > p) se += expf(u2f_ord(uv[rr][t]) - m);
        #pragma unroll
        for (int o = 32; o > 0; o >>= 1) se += __shfl_down(se, o);
        se = __shfl(se, 0);

        mrow[rr] = m;
        tvexp[rr] = expf(u2f_ord(p) - m);
        invz[rr] = 1.0f / (se + (float)ecnt[rr] * tvexp[rr]);
    }

    // ---- weights: attn_out final + wt bf16 (ties in (t,lane) index order) ----
    #pragma unroll
    for (int rr = 0; rr < 2; ++rr) {
        float* aor = aob + (size_t)(2 * wv + rr) * SS;
        unsigned short* wr = wt + (2 * wv + rr) * 1032;
        int tiesbefore = 0;
        #pragma unroll
        for (int t = 0; t < 16; ++t) {
            const unsigned u = uv[rr][t];
            const bool eq = (u == pref[rr]);
            unsigned long long mask = __ballot(eq);
            float w;
            if (u > pref[rr]) {
                w = expf(u2f_ord(u) - mrow[rr]) * invz[rr];
            } else if (eq) {
                int rank = tiesbefore + __popcll(mask & ((1ull << lane) - 1ull));
                w = (rank < ecnt[rr]) ? tvexp[rr] * invz[rr] : 0.f;
            } else {
                w = 0.f;
            }
            aor[t * 64 + lane] = w;
            wr[t * 64 + lane] = f2bf(w);
            tiesbefore += __popcll(mask);
        }
    }

    // ---- PV: ctx[16][128] = W[16][1024] @ V[1024][128], prefetched ----
    f32x4 pacc = {0.f, 0.f, 0.f, 0.f};
    const int pvd = wv * 16 + fc;        // this lane's d column
    su8 rv[2];
    #pragma unroll
    for (int u = 0; u < 2; ++u) {
        int rem = tid + 512 * u;
        int d = rem >> 3, kc = rem & 7;
        rv[u] = *(const su8*)(Vtg + (size_t)d * MROWS + kc * 8);
    }
    for (int t = 0; t < 16; ++t) {
        __syncthreads();   // wt complete (t=0) / prev vt MFMA reads done
        #pragma unroll
        for (int u = 0; u < 2; ++u) {
            int rem = tid + 512 * u;
            int d = rem >> 3, kc = rem & 7;
            *(su8*)&vt[d * 72 + kc * 8] = rv[u];
        }
        if (t < 15) {
            #pragma unroll
            for (int u = 0; u < 2; ++u) {
                int rem = tid + 512 * u;
                int d = rem >> 3, kc = rem & 7;
                rv[u] = *(const su8*)(Vtg + (size_t)d * MROWS +
                                      (t + 1) * 64 + kc * 8);
            }
        }
        __syncthreads();
        #pragma unroll
        for (int kk = 0; kk < 2; ++kk) {
            su8 aw = *(const su8*)&wt[fc * 1032 + t * 64 + (kk * 4 + fg) * 8];
            su8 bv2 = *(const su8*)&vt[pvd * 72 + (kk * 4 + fg) * 8];
            asm volatile("v_mfma_f32_16x16x32_bf16 %0, %1, %2, %0"
                         : "+v"(pacc) : "v"(aw), "v"(bv2));
        }
    }
    asm volatile("s_nop 7\n\ts_nop 7" ::: "memory");

    #pragma unroll
    for (int j = 0; j < 4; ++j)
        CTX[(size_t)(b * SS + q0 + 4 * fg + j) * DD + h * DKK + pvd] = pacc[j];
}

// ---------------------------------------------------------------------------
extern "C" void kernel_launch(void* const* d_in, const int* in_sizes, int n_in,
                              void* d_out, int out_size, void* d_ws, size_t ws_size,
                              hipStream_t stream)
{
    const float* x  = (const float*)d_in[0];
    const float* Wq = (const float*)d_in[1];
    const float* bq = (const float*)d_in[2];
    const float* Wk = (const float*)d_in[3];
    const float* bk = (const float*)d_in[4];
    const float* Wv = (const float*)d_in[5];
    const float* bv = (const float*)d_in[6];
    const float* Wo = (const float*)d_in[7];
    const float* bo = (const float*)d_in[8];

    float* out      = (float*)d_out;                       // [4,1024,2048]
    float* attn_out = (float*)d_out + (size_t)MROWS * DD;  // [4,16,1024,1024]

    float* ws = (float*)d_ws;
    const size_t PLANE = (size_t)MROWS * DD;   // 8,388,608
    // ws carve (134.2 MB, identical to round-9..16):
    float* Qb = ws;
    unsigned short* Ksp = (unsigned short*)(ws + PLANE);
    float* CTX = ws + PLANE + PLANE * 3 / 2;
    unsigned short* Vtp = (unsigned short*)(ws + PLANE + PLANE * 3 / 2 + PLANE);

    dim3 gb(MROWS / TM, DD / TN);   // (32,16)
    gemm_nt_3p<<<gb, 256, 0, stream>>>(x, Wq, bq, Qb, MROWS, DD, DD);
    gemm_nt_3p_ksplit<<<gb, 256, 0, stream>>>(x, Wk, bk, Ksp, MROWS, DD, DD);
    gemm_nt_bf16_tv<<<dim3(DD / TM, MROWS / TN), 256, 0, stream>>>(
        Wv, x, bv, Vtp, DD, MROWS, DD);

    attn_topk_fused<<<dim3(BB * HH * (SS / 16)), 512, 0, stream>>>(
        Qb, Ksp, Vtp, attn_out, CTX);

    gemm_nt_bf16<<<gb, 256, 0, stream>>>(CTX, Wo, bo, out, MROWS, DD, DD);
}

// Round 18
// 986.707 us; speedup vs baseline: 1.2412x; 1.2412x over previous
//
#include <hip/hip_runtime.h>
#include <math.h>

// Problem constants
#define BB 4
#define SS 1024
#define DD 2048
#define HH 16
#define DKK 128
#define KKTOP 307           // int(1024 * 0.3)
#define MROWS (BB * SS)     // 4096
#define KPLANE ((size_t)MROWS * DD)   // elements per K-split plane (8,388,608)
static __device__ __constant__ float SCALE = 0.08838834764831845f; // 1/sqrt(128)

typedef float f32x4 __attribute__((ext_vector_type(4)));
typedef unsigned short su4 __attribute__((ext_vector_type(4)));
typedef unsigned short su8 __attribute__((ext_vector_type(8)));

__device__ __forceinline__ unsigned short f2bf(float x) {   // RNE
    unsigned u = __float_as_uint(x);
    u += 0x7fffu + ((u >> 16) & 1u);
    return (unsigned short)(u >> 16);
}
__device__ __forceinline__ float bf2f(unsigned short b) {
    return __uint_as_float((unsigned)b << 16);
}
__device__ __forceinline__ unsigned f2u_ord(float f) {
    unsigned x = __float_as_uint(f);
    return (x & 0x80000000u) ? ~x : (x | 0x80000000u);
}
__device__ __forceinline__ float u2f_ord(unsigned u) {
    return __uint_as_float((u & 0x80000000u) ? (u & 0x7fffffffu) : ~u);
}
// 3-way bf16 split of fp32 (captures ~24 mantissa bits)
__device__ __forceinline__ void split4(float4 v, su4& a, su4& b, su4& c) {
    float x[4] = {v.x, v.y, v.z, v.w};
    #pragma unroll
    for (int i = 0; i < 4; ++i) {
        unsigned short b1 = f2bf(x[i]);
        float r = x[i] - bf2f(b1);
        unsigned short b2 = f2bf(r);
        float r2 = r - bf2f(b2);
        a[i] = b1; b[i] = b2; c[i] = f2bf(r2);
    }
}
// 2-way bf16 split of fp32 (residual <= 2^-9 |x|)
__device__ __forceinline__ void split2_4(float4 v, su4& a, su4& b) {
    float x[4] = {v.x, v.y, v.z, v.w};
    #pragma unroll
    for (int i = 0; i < 4; ++i) {
        unsigned short b1 = f2bf(x[i]);
        float r = x[i] - bf2f(b1);
        a[i] = b1; b[i] = f2bf(r);
    }
}
__device__ __forceinline__ su8 cat44(su4 a, su4 b) {
    su8 r;
    r[0] = a[0]; r[1] = a[1]; r[2] = a[2]; r[3] = a[3];
    r[4] = b[0]; r[5] = b[1]; r[6] = b[2]; r[7] = b[3];
    return r;
}

#define TM 128
#define TN 128

// ---------------------------------------------------------------------------
// GEMM 3-pass split-bf16 MFMA (round-12 verified, verbatim). Used for Q.
// ---------------------------------------------------------------------------
#define G3LD 40

__global__ __launch_bounds__(256) void gemm_nt_3p(
    const float* __restrict__ A, const float* __restrict__ W,
    const float* __restrict__ bias, float* __restrict__ C,
    int M, int N, int K)
{
    __shared__ unsigned short A1[128][G3LD];
    __shared__ unsigned short A2[128][G3LD];
    __shared__ unsigned short B1[128][G3LD];
    __shared__ unsigned short B2[128][G3LD];

    const int tid = threadIdx.x;
    const int bm = blockIdx.x * 128;
    const int bn = blockIdx.y * 128;
    const int wm = (tid >> 6) & 1;
    const int wn = tid >> 7;
    const int lane = tid & 63;
    const int lrow = tid >> 1;
    const int lcol = (tid & 1) * 16;

    f32x4 acc[4][4];
    #pragma unroll
    for (int i = 0; i < 4; ++i)
        #pragma unroll
        for (int j = 0; j < 4; ++j)
            acc[i][j] = (f32x4){0.f, 0.f, 0.f, 0.f};

    for (int kt = 0; kt < K; kt += 32) {
        __syncthreads();
        {
            const float* Ag = A + (size_t)(bm + lrow) * K + kt + lcol;
            const float* Wg = W + (size_t)(bn + lrow) * K + kt + lcol;
            float4 v0, v1; su4 h0, l0, h1, l1;
            v0 = *(const float4*)(Ag + 0);  v1 = *(const float4*)(Ag + 4);
            split2_4(v0, h0, l0); split2_4(v1, h1, l1);
            *(su8*)&A1[lrow][lcol + 0] = cat44(h0, h1);
            *(su8*)&A2[lrow][lcol + 0] = cat44(l0, l1);
            v0 = *(const float4*)(Ag + 8);  v1 = *(const float4*)(Ag + 12);
            split2_4(v0, h0, l0); split2_4(v1, h1, l1);
            *(su8*)&A1[lrow][lcol + 8] = cat44(h0, h1);
            *(su8*)&A2[lrow][lcol + 8] = cat44(l0, l1);
            v0 = *(const float4*)(Wg + 0);  v1 = *(const float4*)(Wg + 4);
            split2_4(v0, h0, l0); split2_4(v1, h1, l1);
            *(su8*)&B1[lrow][lcol + 0] = cat44(h0, h1);
            *(su8*)&B2[lrow][lcol + 0] = cat44(l0, l1);
            v0 = *(const float4*)(Wg + 8);  v1 = *(const float4*)(Wg + 12);
            split2_4(v0, h0, l0); split2_4(v1, h1, l1);
            *(su8*)&B1[lrow][lcol + 8] = cat44(h0, h1);
            *(su8*)&B2[lrow][lcol + 8] = cat44(l0, l1);
        }
        __syncthreads();

        su8 a1[4], a2[4], b1[4], b2[4];
        #pragma unroll
        for (int f = 0; f < 4; ++f) {
            const int fr = f * 16 + (lane & 15);
            const int fk = (lane >> 4) * 8;
            a1[f] = *(const su8*)&A1[wm * 64 + fr][fk];
            a2[f] = *(const su8*)&A2[wm * 64 + fr][fk];
            b1[f] = *(const su8*)&B1[wn * 64 + fr][fk];
            b2[f] = *(const su8*)&B2[wn * 64 + fr][fk];
        }
        #pragma unroll
        for (int fi = 0; fi < 4; ++fi)
            #pragma unroll
            for (int fj = 0; fj < 4; ++fj) {
                asm volatile("v_mfma_f32_16x16x32_bf16 %0, %1, %2, %0"
                             : "+v"(acc[fi][fj]) : "v"(a1[fi]), "v"(b2[fj]));
                asm volatile("v_mfma_f32_16x16x32_bf16 %0, %1, %2, %0"
                             : "+v"(acc[fi][fj]) : "v"(a2[fi]), "v"(b1[fj]));
                asm volatile("v_mfma_f32_16x16x32_bf16 %0, %1, %2, %0"
                             : "+v"(acc[fi][fj]) : "v"(a1[fi]), "v"(b1[fj]));
            }
    }

    asm volatile("s_nop 7\n\ts_nop 7" ::: "memory");

    #pragma unroll
    for (int fj = 0; fj < 4; ++fj) {
        const int col = bn + wn * 64 + fj * 16 + (lane & 15);
        const float bv = bias[col];
        #pragma unroll
        for (int fi = 0; fi < 4; ++fi) {
            const int r0 = bm + wm * 64 + fi * 16 + (lane >> 4) * 4;
            #pragma unroll
            for (int j = 0; j < 4; ++j)
                C[(size_t)(r0 + j) * N + col] = acc[fi][fj][j] + bv;
        }
    }
}

// ---------------------------------------------------------------------------
// Same 3-pass core, K-split epilogue (round-12 verified, verbatim).
// ---------------------------------------------------------------------------
__global__ __launch_bounds__(256) void gemm_nt_3p_ksplit(
    const float* __restrict__ A, const float* __restrict__ W,
    const float* __restrict__ bias, unsigned short* __restrict__ Ks,
    int M, int N, int K)
{
    __shared__ unsigned short A1[128][G3LD];
    __shared__ unsigned short A2[128][G3LD];
    __shared__ unsigned short B1[128][G3LD];
    __shared__ unsigned short B2[128][G3LD];

    const int tid = threadIdx.x;
    const int bm = blockIdx.x * 128;
    const int bn = blockIdx.y * 128;
    const int wm = (tid >> 6) & 1;
    const int wn = tid >> 7;
    const int lane = tid & 63;
    const int lrow = tid >> 1;
    const int lcol = (tid & 1) * 16;

    f32x4 acc[4][4];
    #pragma unroll
    for (int i = 0; i < 4; ++i)
        #pragma unroll
        for (int j = 0; j < 4; ++j)
            acc[i][j] = (f32x4){0.f, 0.f, 0.f, 0.f};

    for (int kt = 0; kt < K; kt += 32) {
        __syncthreads();
        {
            const float* Ag = A + (size_t)(bm + lrow) * K + kt + lcol;
            const float* Wg = W + (size_t)(bn + lrow) * K + kt + lcol;
            float4 v0, v1; su4 h0, l0, h1, l1;
            v0 = *(const float4*)(Ag + 0);  v1 = *(const float4*)(Ag + 4);
            split2_4(v0, h0, l0); split2_4(v1, h1, l1);
            *(su8*)&A1[lrow][lcol + 0] = cat44(h0, h1);
            *(su8*)&A2[lrow][lcol + 0] = cat44(l0, l1);
            v0 = *(const float4*)(Ag + 8);  v1 = *(const float4*)(Ag + 12);
            split2_4(v0, h0, l0); split2_4(v1, h1, l1);
            *(su8*)&A1[lrow][lcol + 8] = cat44(h0, h1);
            *(su8*)&A2[lrow][lcol + 8] = cat44(l0, l1);
            v0 = *(const float4*)(Wg + 0);  v1 = *(const float4*)(Wg + 4);
            split2_4(v0, h0, l0); split2_4(v1, h1, l1);
            *(su8*)&B1[lrow][lcol + 0] = cat44(h0, h1);
            *(su8*)&B2[lrow][lcol + 0] = cat44(l0, l1);
            v0 = *(const float4*)(Wg + 8);  v1 = *(const float4*)(Wg + 12);
            split2_4(v0, h0, l0); split2_4(v1, h1, l1);
            *(su8*)&B1[lrow][lcol + 8] = cat44(h0, h1);
            *(su8*)&B2[lrow][lcol + 8] = cat44(l0, l1);
        }
        __syncthreads();

        su8 a1[4], a2[4], b1[4], b2[4];
        #pragma unroll
        for (int f = 0; f < 4; ++f) {
            const int fr = f * 16 + (lane & 15);
            const int fk = (lane >> 4) * 8;
            a1[f] = *(const su8*)&A1[wm * 64 + fr][fk];
            a2[f] = *(const su8*)&A2[wm * 64 + fr][fk];
            b1[f] = *(const su8*)&B1[wn * 64 + fr][fk];
            b2[f] = *(const su8*)&B2[wn * 64 + fr][fk];
        }
        #pragma unroll
        for (int fi = 0; fi < 4; ++fi)
            #pragma unroll
            for (int fj = 0; fj < 4; ++fj) {
                asm volatile("v_mfma_f32_16x16x32_bf16 %0, %1, %2, %0"
                             : "+v"(acc[fi][fj]) : "v"(a1[fi]), "v"(b2[fj]));
                asm volatile("v_mfma_f32_16x16x32_bf16 %0, %1, %2, %0"
                             : "+v"(acc[fi][fj]) : "v"(a2[fi]), "v"(b1[fj]));
                asm volatile("v_mfma_f32_16x16x32_bf16 %0, %1, %2, %0"
                             : "+v"(acc[fi][fj]) : "v"(a1[fi]), "v"(b1[fj]));
            }
    }

    asm volatile("s_nop 7\n\ts_nop 7" ::: "memory");

    #pragma unroll
    for (int fj = 0; fj < 4; ++fj) {
        const int col = bn + wn * 64 + fj * 16 + (lane & 15);
        const int h = col >> 7, d = col & (DKK - 1);
        const float bv = bias[col];
        #pragma unroll
        for (int fi = 0; fi < 4; ++fi) {
            const int r0 = bm + wm * 64 + fi * 16 + (lane >> 4) * 4;
            #pragma unroll
            for (int j = 0; j < 4; ++j) {
                const int tok = r0 + j;
                const float val = acc[fi][fj][j] + bv;
                const size_t o = ((size_t)((tok >> 10) * HH + h) * SS
                                  + (tok & (SS - 1))) * DKK + d;
                unsigned short s1 = f2bf(val);
                float r = val - bf2f(s1);
                unsigned short s2 = f2bf(r);
                float r2 = r - bf2f(s2);
                Ks[0 * KPLANE + o] = s1;
                Ks[1 * KPLANE + o] = s2;
                Ks[2 * KPLANE + o] = f2bf(r2);
            }
        }
    }
}

// ---------------------------------------------------------------------------
// GEMM bf16-MFMA (round-6 verified, verbatim): fp32 in/out. Used for O-proj.
// ---------------------------------------------------------------------------
#define GLDA 40

__device__ __forceinline__ su8 pack8(float4 x, float4 y) {
    su8 r;
    r[0] = f2bf(x.x); r[1] = f2bf(x.y); r[2] = f2bf(x.z); r[3] = f2bf(x.w);
    r[4] = f2bf(y.x); r[5] = f2bf(y.y); r[6] = f2bf(y.z); r[7] = f2bf(y.w);
    return r;
}

__global__ __launch_bounds__(256) void gemm_nt_bf16(
    const float* __restrict__ A, const float* __restrict__ W,
    const float* __restrict__ bias, float* __restrict__ C,
    int M, int N, int K)
{
    __shared__ unsigned short Ab[128][GLDA];
    __shared__ unsigned short Bb[128][GLDA];

    const int tid = threadIdx.x;
    const int bm = blockIdx.x * 128;
    const int bn = blockIdx.y * 128;
    const int wm = (tid >> 6) & 1;
    const int wn = tid >> 7;
    const int lane = tid & 63;
    const int lrow = tid >> 1;
    const int lcol = (tid & 1) * 16;

    f32x4 acc[4][4];
    #pragma unroll
    for (int i = 0; i < 4; ++i)
        #pragma unroll
        for (int j = 0; j < 4; ++j)
            acc[i][j] = (f32x4){0.f, 0.f, 0.f, 0.f};

    for (int kt = 0; kt < K; kt += 32) {
        __syncthreads();
        {
            const float* Ag = A + (size_t)(bm + lrow) * K + kt + lcol;
            const float* Wg = W + (size_t)(bn + lrow) * K + kt + lcol;
            float4 a0 = *(const float4*)(Ag + 0);
            float4 a1 = *(const float4*)(Ag + 4);
            float4 a2 = *(const float4*)(Ag + 8);
            float4 a3 = *(const float4*)(Ag + 12);
            *(su8*)&Ab[lrow][lcol + 0] = pack8(a0, a1);
            *(su8*)&Ab[lrow][lcol + 8] = pack8(a2, a3);
            float4 b0 = *(const float4*)(Wg + 0);
            float4 b1 = *(const float4*)(Wg + 4);
            float4 b2 = *(const float4*)(Wg + 8);
            float4 b3 = *(const float4*)(Wg + 12);
            *(su8*)&Bb[lrow][lcol + 0] = pack8(b0, b1);
            *(su8*)&Bb[lrow][lcol + 8] = pack8(b2, b3);
        }
        __syncthreads();

        su8 af[4], bf[4];
        #pragma unroll
        for (int f = 0; f < 4; ++f) {
            af[f] = *(const su8*)&Ab[wm * 64 + f * 16 + (lane & 15)][(lane >> 4) * 8];
            bf[f] = *(const su8*)&Bb[wn * 64 + f * 16 + (lane & 15)][(lane >> 4) * 8];
        }
        #pragma unroll
        for (int fi = 0; fi < 4; ++fi)
            #pragma unroll
            for (int fj = 0; fj < 4; ++fj)
                asm volatile("v_mfma_f32_16x16x32_bf16 %0, %1, %2, %0"
                             : "+v"(acc[fi][fj])
                             : "v"(af[fi]), "v"(bf[fj]));
    }

    asm volatile("s_nop 7\n\ts_nop 7" ::: "memory");

    #pragma unroll
    for (int fj = 0; fj < 4; ++fj) {
        const int col = bn + wn * 64 + fj * 16 + (lane & 15);
        const float bv = bias[col];
        #pragma unroll
        for (int fi = 0; fi < 4; ++fi) {
            const int r0 = bm + wm * 64 + fi * 16 + (lane >> 4) * 4;
            #pragma unroll
            for (int j = 0; j < 4; ++j)
                C[(size_t)(r0 + j) * N + col] = acc[fi][fj][j] + bv;
        }
    }
}

// ---------------------------------------------------------------------------
// GEMM bf16-MFMA, transposed-V variant (round-8 verified, verbatim).
// ---------------------------------------------------------------------------
__global__ __launch_bounds__(256) void gemm_nt_bf16_tv(
    const float* __restrict__ A, const float* __restrict__ W,
    const float* __restrict__ bias, unsigned short* __restrict__ Cb,
    int M, int N, int K)
{
    __shared__ unsigned short Ab[128][GLDA];
    __shared__ unsigned short Bb[128][GLDA];

    const int tid = threadIdx.x;
    const int bm = blockIdx.x * 128;
    const int bn = blockIdx.y * 128;
    const int wm = (tid >> 6) & 1;
    const int wn = tid >> 7;
    const int lane = tid & 63;
    const int lrow = tid >> 1;
    const int lcol = (tid & 1) * 16;

    f32x4 acc[4][4];
    #pragma unroll
    for (int i = 0; i < 4; ++i)
        #pragma unroll
        for (int j = 0; j < 4; ++j)
            acc[i][j] = (f32x4){0.f, 0.f, 0.f, 0.f};

    for (int kt = 0; kt < K; kt += 32) {
        __syncthreads();
        {
            const float* Ag = A + (size_t)(bm + lrow) * K + kt + lcol;
            const float* Wg = W + (size_t)(bn + lrow) * K + kt + lcol;
            float4 a0 = *(const float4*)(Ag + 0);
            float4 a1 = *(const float4*)(Ag + 4);
            float4 a2 = *(const float4*)(Ag + 8);
            float4 a3 = *(const float4*)(Ag + 12);
            *(su8*)&Ab[lrow][lcol + 0] = pack8(a0, a1);
            *(su8*)&Ab[lrow][lcol + 8] = pack8(a2, a3);
            float4 b0 = *(const float4*)(Wg + 0);
            float4 b1 = *(const float4*)(Wg + 4);
            float4 b2 = *(const float4*)(Wg + 8);
            float4 b3 = *(const float4*)(Wg + 12);
            *(su8*)&Bb[lrow][lcol + 0] = pack8(b0, b1);
            *(su8*)&Bb[lrow][lcol + 8] = pack8(b2, b3);
        }
        __syncthreads();

        su8 af[4], bf[4];
        #pragma unroll
        for (int f = 0; f < 4; ++f) {
            af[f] = *(const su8*)&Ab[wm * 64 + f * 16 + (lane & 15)][(lane >> 4) * 8];
            bf[f] = *(const su8*)&Bb[wn * 64 + f * 16 + (lane & 15)][(lane >> 4) * 8];
        }
        #pragma unroll
        for (int fi = 0; fi < 4; ++fi)
            #pragma unroll
            for (int fj = 0; fj < 4; ++fj)
                asm volatile("v_mfma_f32_16x16x32_bf16 %0, %1, %2, %0"
                             : "+v"(acc[fi][fj])
                             : "v"(af[fi]), "v"(bf[fj]));
    }

    asm volatile("s_nop 7\n\ts_nop 7" ::: "memory");

    #pragma unroll
    for (int fj = 0; fj < 4; ++fj) {
        const int col = bn + wn * 64 + fj * 16 + (lane & 15);
        #pragma unroll
        for (int fi = 0; fi < 4; ++fi) {
            const int r0 = bm + wm * 64 + fi * 16 + (lane >> 4) * 4;
            #pragma unroll
            for (int j = 0; j < 4; ++j) {
                float v = acc[fi][fj][j] + bias[r0 + j];
                Cb[(size_t)(r0 + j) * N + col] = f2bf(v);
            }
        }
    }
}

// ---------------------------------------------------------------------------
// Fused attn — round-13 anchor, verbatim (best measured: attn ~525 us,
// total ~983 us). Four orthogonal variants all measured worse:
//   r10 geometry rewrite (failed validation), r14 LDS-transpose traffic cut
//   (-450 MB HBM but occupancy 46->24, +217 us), r15 per-lane global staging
//   (occupancy 69 but FETCH x8.5, +425 us), r17 stride-140 de-banking
//   (conflicts halved but 280 B misaligns b128 -> split ops, +250 us).
// Constraints pinning this design: >=2 blocks/CU concurrency, fully
// coalesced staging, 16B-aligned LDS strides, <=64 KB LDS.
// ---------------------------------------------------------------------------
#define ATT_LDS 65280

__global__ __launch_bounds__(512) void attn_topk_fused(
    const float* __restrict__ Qb, const unsigned short* __restrict__ Ks,
    const unsigned short* __restrict__ Vt, float* __restrict__ attn_out,
    float* __restrict__ CTX)
{
    __shared__ __align__(16) char smem[ATT_LDS];
    unsigned short* q_s = (unsigned short*)smem;                   // [3][16][136]
    unsigned short* k_s = (unsigned short*)(smem + 13056);         // [3][64][136]
    float*          red = (float*)smem;                            // [4][16][16]
    unsigned short* wt  = (unsigned short*)(smem + 13056);         // [16][1032]
    unsigned short* vt  = (unsigned short*)(smem + 13056 + 33024); // [128][72]

    const int tid = threadIdx.x;
    const int wv = tid >> 6, lane = tid & 63;
    const int fg = lane >> 4, fc = lane & 15;

    // XCD-chunked bijective remap: 4096 = 8 XCDs x 512
    const int gg = (blockIdx.x & 7) * 512 + ((int)blockIdx.x >> 3);
    const int bh = gg >> 6, qb = gg & 63;
    const int b = bh >> 4, h = bh & 15;
    const int q0 = qb * 16;

    const float* Qg = Qb + (size_t)(b * SS + q0) * DD + h * DKK;
    const unsigned short* Ksg = Ks + (size_t)bh * SS * DKK;
    const unsigned short* Vtg = Vt + (size_t)(h * DKK) * MROWS + b * SS;
    float* aob = attn_out + (size_t)(bh * SS + q0) * SS;

    // ---- issue K tile-0 prefetch before Q staging (overlaps) ----
    su8 rk[6];
    #pragma unroll
    for (int pu = 0; pu < 6; ++pu) {
        const int p = pu >> 1;
        const int rem = tid + 512 * (pu & 1);
        const int row = rem >> 4, c8 = rem & 15;
        rk[pu] = *(const su8*)(Ksg + p * KPLANE +
                               (size_t)row * DKK + c8 * 8);
    }

    // ---- stage Q splits (once): 512 units = 16 rows x 32 c4 ----
    {
        int row = tid >> 5, c4 = tid & 31;
        float4 v = *(const float4*)(Qg + (size_t)row * DD + c4 * 4);
        int off = row * 136 + c4 * 4;
        su4 p1, p2, p3; split4(v, p1, p2, p3);
        *(su4*)&q_s[off] = p1;
        *(su4*)&q_s[2176 + off] = p2;
        *(su4*)&q_s[4352 + off] = p3;
    }
    __syncthreads();

    // ---- persistent A-frags: af[split][ktile-of-my-dhalf] ----
    const int kt0 = (wv >> 2) * 2;   // ktile base: 0 (d 0..63) or 2 (d 64..127)
    su8 af[3][2];
    #pragma unroll
    for (int p = 0; p < 3; ++p)
        #pragma unroll
        for (int kk = 0; kk < 2; ++kk)
            af[p][kk] = *(const su8*)&q_s[p * 2176 + fc * 136 +
                            ((kt0 + kk) * 4 + fg) * 8];

    // ---- scores over 16 key-tiles of 64 (prefetched pipeline) ----
    unsigned uv[2][16];
    for (int t = 0; t < 16; ++t) {
        // write prefetched tile t (k_s reads of t-1 done before barrier-2(t-1))
        #pragma unroll
        for (int pu = 0; pu < 6; ++pu) {
            const int p = pu >> 1;
            const int rem = tid + 512 * (pu & 1);
            const int row = rem >> 4, c8 = rem & 15;
            *(su8*)&k_s[p * 8704 + row * 136 + c8 * 8] = rk[pu];
        }
        // issue loads for tile t+1 (fly during MFMA + barriers)
        if (t < 15) {
            #pragma unroll
            for (int pu = 0; pu < 6; ++pu) {
                const int p = pu >> 1;
                const int rem = tid + 512 * (pu & 1);
                const int row = rem >> 4, c8 = rem & 15;
                rk[pu] = *(const su8*)(Ksg + p * KPLANE +
                            (size_t)((t + 1) * 64 + row) * DKK + c8 * 8);
            }
        }
        __syncthreads();   // barrier-1: k_s tile t visible

        const int krow = (wv & 3) * 16 + fc;
        su8 bf[3][2];
        #pragma unroll
        for (int p = 0; p < 3; ++p)
            #pragma unroll
            for (int kk = 0; kk < 2; ++kk)
                bf[p][kk] = *(const su8*)&k_s[p * 8704 + krow * 136 +
                                ((kt0 + kk) * 4 + fg) * 8];

        f32x4 acc = {0.f, 0.f, 0.f, 0.f};
        // passes small->large: (q3,k1),(q1,k3),(q2,k2),(q2,k1),(q1,k2),(q1,k1)
        constexpr int PI[6] = {2, 0, 1, 1, 0, 0};
        constexpr int PJ[6] = {0, 2, 1, 0, 1, 0};
        #pragma unroll
        for (int p = 0; p < 6; ++p)
            #pragma unroll
            for (int kk = 0; kk < 2; ++kk)
                asm volatile("v_mfma_f32_16x16x32_bf16 %0, %1, %2, %0"
                             : "+v"(acc) : "v"(af[PI[p]][kk]), "v"(bf[PJ[p]][kk]));
        asm volatile("s_nop 7\n\ts_nop 7" ::: "memory");

        if (kt0 == 2) {
            #pragma unroll
            for (int j = 0; j < 4; ++j)
                red[(wv & 3) * 256 + (4 * fg + j) * 16 + fc] = acc[j];
        }
        __syncthreads();   // barrier-2: red visible; k_s reads done
        if (kt0 == 0) {
            #pragma unroll
            for (int j = 0; j < 4; ++j) {
                float s = (acc[j] + red[(wv & 3) * 256 + (4 * fg + j) * 16 + fc]) * SCALE;
                aob[(size_t)(4 * fg + j) * SS + t * 64 + (wv & 3) * 16 + fc] = s;
            }
        }
    }
    __syncthreads();  // all scores visible within block

    // ---- selection + softmax params (verified ballot bit-descent), 2 rows ----
    #pragma unroll
    for (int rr = 0; rr < 2; ++rr) {
        const float* aor = aob + (size_t)(2 * wv + rr) * SS;
        #pragma unroll
        for (int t = 0; t < 16; ++t)
            uv[rr][t] = f2u_ord(aor[t * 64 + lane]);
    }
    unsigned pref[2]; int ecnt[2]; float mrow[2], invz[2], tvexp[2];
    #pragma unroll
    for (int rr = 0; rr < 2; ++rr) {
        unsigned p = 0;
        for (int bit = 31; bit >= 0; --bit) {
            unsigned cand = p | (1u << bit);
            int cnt = 0;
            #pragma unroll
            for (int t = 0; t < 16; ++t)
                cnt += __popcll(__ballot(uv[rr][t] >= cand));
            if (cnt >= KKTOP) p = cand;
        }
        pref[rr] = p;
        int g = 0;
        #pragma unroll
        for (int t = 0; t < 16; ++t)
            g += __popcll(__ballot(uv[rr][t] > p));
        ecnt[rr] = KKTOP - g;

        unsigned um = 0;
        #pragma unroll
        for (int t = 0; t < 16; ++t) um = um > uv[rr][t] ? um : uv[rr][t];
        #pragma unroll
        for (int o = 32; o > 0; o >>= 1) {
            unsigned tv2 = __shfl_down(um, o);
            um = um > tv2 ? um : tv2;
        }
        um = __shfl(um, 0);
        const float m = u2f_ord(um);

        float se = 0.f;
        #pragma unroll
        for (int t = 0; t < 16; ++t)
            if (uv[rr][t] > p) se += expf(u2f_ord(uv[rr][t]) - m);
        #pragma unroll
        for (int o = 32; o > 0; o >>= 1) se += __shfl_down(se, o);
        se = __shfl(se, 0);

        mrow[rr] = m;
        tvexp[rr] = expf(u2f_ord(p) - m);
        invz[rr] = 1.0f / (se + (float)ecnt[rr] * tvexp[rr]);
    }

    // ---- weights: attn_out final + wt bf16 (ties in (t,lane) index order) ----
    #pragma unroll
    for (int rr = 0; rr < 2; ++rr) {
        float* aor = aob + (size_t)(2 * wv + rr) * SS;
        unsigned short* wr = wt + (2 * wv + rr) * 1032;
        int tiesbefore = 0;
        #pragma unroll
        for (int t = 0; t < 16; ++t) {
            const unsigned u = uv[rr][t];
            const bool eq = (u == pref[rr]);
            unsigned long long mask = __ballot(eq);
            float w;
            if (u > pref[rr]) {
                w = expf(u2f_ord(u) - mrow[rr]) * invz[rr];
            } else if (eq) {
                int rank = tiesbefore + __popcll(mask & ((1ull << lane) - 1ull));
                w = (rank < ecnt[rr]) ? tvexp[rr] * invz[rr] : 0.f;
            } else {
                w = 0.f;
            }
            aor[t * 64 + lane] = w;
            wr[t * 64 + lane] = f2bf(w);
            tiesbefore += __popcll(mask);
        }
    }

    // ---- PV: ctx[16][128] = W[16][1024] @ V[1024][128], prefetched ----
    f32x4 pacc = {0.f, 0.f, 0.f, 0.f};
    const int pvd = wv * 16 + fc;        // this lane's d column
    su8 rv[2];
    #pragma unroll
    for (int u = 0; u < 2; ++u) {
        int rem = tid + 512 * u;
        int d = rem >> 3, kc = rem & 7;
        rv[u] = *(const su8*)(Vtg + (size_t)d * MROWS + kc * 8);
    }
    for (int t = 0; t < 16; ++t) {
        __syncthreads();   // wt complete (t=0) / prev vt MFMA reads done
        #pragma unroll
        for (int u = 0; u < 2; ++u) {
            int rem = tid + 512 * u;
            int d = rem >> 3, kc = rem & 7;
            *(su8*)&vt[d * 72 + kc * 8] = rv[u];
        }
        if (t < 15) {
            #pragma unroll
            for (int u = 0; u < 2; ++u) {
                int rem = tid + 512 * u;
                int d = rem >> 3, kc = rem & 7;
                rv[u] = *(const su8*)(Vtg + (size_t)d * MROWS +
                                      (t + 1) * 64 + kc * 8);
            }
        }
        __syncthreads();
        #pragma unroll
        for (int kk = 0; kk < 2; ++kk) {
            su8 aw = *(const su8*)&wt[fc * 1032 + t * 64 + (kk * 4 + fg) * 8];
            su8 bv2 = *(const su8*)&vt[pvd * 72 + (kk * 4 + fg) * 8];
            asm volatile("v_mfma_f32_16x16x32_bf16 %0, %1, %2, %0"
                         : "+v"(pacc) : "v"(aw), "v"(bv2));
        }
    }
    asm volatile("s_nop 7\n\ts_nop 7" ::: "memory");

    #pragma unroll
    for (int j = 0; j < 4; ++j)
        CTX[(size_t)(b * SS + q0 + 4 * fg + j) * DD + h * DKK + pvd] = pacc[j];
}

// ---------------------------------------------------------------------------
extern "C" void kernel_launch(void* const* d_in, const int* in_sizes, int n_in,
                              void* d_out, int out_size, void* d_ws, size_t ws_size,
                              hipStream_t stream)
{
    const float* x  = (const float*)d_in[0];
    const float* Wq = (const float*)d_in[1];
    const float* bq = (const float*)d_in[2];
    const float* Wk = (const float*)d_in[3];
    const float* bk = (const float*)d_in[4];
    const float* Wv = (const float*)d_in[5];
    const float* bv = (const float*)d_in[6];
    const float* Wo = (const float*)d_in[7];
    const float* bo = (const float*)d_in[8];

    float* out      = (float*)d_out;                       // [4,1024,2048]
    float* attn_out = (float*)d_out + (size_t)MROWS * DD;  // [4,16,1024,1024]

    float* ws = (float*)d_ws;
    const size_t PLANE = (size_t)MROWS * DD;   // 8,388,608
    // ws carve (134.2 MB, identical to round-9..16):
    float* Qb = ws;
    unsigned short* Ksp = (unsigned short*)(ws + PLANE);
    float* CTX = ws + PLANE + PLANE * 3 / 2;
    unsigned short* Vtp = (unsigned short*)(ws + PLANE + PLANE * 3 / 2 + PLANE);

    dim3 gb(MROWS / TM, DD / TN);   // (32,16)
    gemm_nt_3p<<<gb, 256, 0, stream>>>(x, Wq, bq, Qb, MROWS, DD, DD);
    gemm_nt_3p_ksplit<<<gb, 256, 0, stream>>>(x, Wk, bk, Ksp, MROWS, DD, DD);
    gemm_nt_bf16_tv<<<dim3(DD / TM, MROWS / TN), 256, 0, stream>>>(
        Wv, x, bv, Vtp, DD, MROWS, DD);

    attn_topk_fused<<<dim3(BB * HH * (SS / 16)), 512, 0, stream>>>(
        Qb, Ksp, Vtp, attn_out, CTX);

    gemm_nt_bf16<<<gb, 256, 0, stream>>>(CTX, Wo, bo, out, MROWS, DD, DD);
}

// Round 19
// 913.780 us; speedup vs baseline: 1.3403x; 1.0798x over previous
//
#include <hip/hip_runtime.h>
#include <math.h>

// Problem constants
#define BB 4
#define SS 1024
#define DD 2048
#define HH 16
#define DKK 128
#define KKTOP 307           // int(1024 * 0.3)
#define MROWS (BB * SS)     // 4096
#define KPLANE ((size_t)MROWS * DD)   // elements per K-split plane (8,388,608)
static __device__ __constant__ float SCALE = 0.08838834764831845f; // 1/sqrt(128)

typedef float f32x4 __attribute__((ext_vector_type(4)));
typedef unsigned short su4 __attribute__((ext_vector_type(4)));
typedef unsigned short su8 __attribute__((ext_vector_type(8)));

__device__ __forceinline__ unsigned short f2bf(float x) {   // RNE
    unsigned u = __float_as_uint(x);
    u += 0x7fffu + ((u >> 16) & 1u);
    return (unsigned short)(u >> 16);
}
__device__ __forceinline__ float bf2f(unsigned short b) {
    return __uint_as_float((unsigned)b << 16);
}
__device__ __forceinline__ unsigned f2u_ord(float f) {
    unsigned x = __float_as_uint(f);
    return (x & 0x80000000u) ? ~x : (x | 0x80000000u);
}
__device__ __forceinline__ float u2f_ord(unsigned u) {
    return __uint_as_float((u & 0x80000000u) ? (u & 0x7fffffffu) : ~u);
}
// 3-way bf16 split of fp32 (captures ~24 mantissa bits)
__device__ __forceinline__ void split4(float4 v, su4& a, su4& b, su4& c) {
    float x[4] = {v.x, v.y, v.z, v.w};
    #pragma unroll
    for (int i = 0; i < 4; ++i) {
        unsigned short b1 = f2bf(x[i]);
        float r = x[i] - bf2f(b1);
        unsigned short b2 = f2bf(r);
        float r2 = r - bf2f(b2);
        a[i] = b1; b[i] = b2; c[i] = f2bf(r2);
    }
}
// 2-way bf16 split of fp32 (residual <= 2^-9 |x|)
__device__ __forceinline__ void split2_4(float4 v, su4& a, su4& b) {
    float x[4] = {v.x, v.y, v.z, v.w};
    #pragma unroll
    for (int i = 0; i < 4; ++i) {
        unsigned short b1 = f2bf(x[i]);
        float r = x[i] - bf2f(b1);
        a[i] = b1; b[i] = f2bf(r);
    }
}
__device__ __forceinline__ su8 cat44(su4 a, su4 b) {
    su8 r;
    r[0] = a[0]; r[1] = a[1]; r[2] = a[2]; r[3] = a[3];
    r[4] = b[0]; r[5] = b[1]; r[6] = b[2]; r[7] = b[3];
    return r;
}
__device__ __forceinline__ su8 pack8(float4 x, float4 y) {
    su8 r;
    r[0] = f2bf(x.x); r[1] = f2bf(x.y); r[2] = f2bf(x.z); r[3] = f2bf(x.w);
    r[4] = f2bf(y.x); r[5] = f2bf(y.y); r[6] = f2bf(y.z); r[7] = f2bf(y.w);
    return r;
}

#define TM 128
#define TN 128
#define G3LD 40

// ---------------------------------------------------------------------------
// Fused QKV projection: one 1536-block dispatch replacing 3 serial kernels
// (saves two kernel-boundary tails; bodies are the round-12/8-verified
// cores VERBATIM, only the block-index decode differs).
//   zone [0,512):    Q = x@Wq^T+bq, 3-pass split-bf16 core, fp32 out
//   zone [512,1024): K = x@Wk^T+bk, 3-pass core + 3-plane ksplit epilogue
//   zone [1024,1536): Vt = (Wv@x^T+bv[row]) bf16 out, 1-pass core
// LDS: union, 40 KB (3p: A1/A2/B1/B2 @ 0/10240/20480/30720; 1p: Ab/Bb).
// ---------------------------------------------------------------------------
__global__ __launch_bounds__(256) void qkv_proj(
    const float* __restrict__ x,
    const float* __restrict__ Wq, const float* __restrict__ bq,
    const float* __restrict__ Wk, const float* __restrict__ bk,
    const float* __restrict__ Wv, const float* __restrict__ bv,
    float* __restrict__ Qb, unsigned short* __restrict__ Ks,
    unsigned short* __restrict__ Vt)
{
    __shared__ __align__(16) char sm[40960];

    const int tid = threadIdx.x;
    const int id = blockIdx.x;
    const int wm = (tid >> 6) & 1;
    const int wn = tid >> 7;
    const int lane = tid & 63;
    const int lrow = tid >> 1;
    const int lcol = (tid & 1) * 16;
    const int K = DD;

    if (id < 1024) {
        // ================= 3-pass zones: Q (id<512) / K =================
        unsigned short (*A1)[G3LD] = (unsigned short (*)[G3LD])(sm);
        unsigned short (*A2)[G3LD] = (unsigned short (*)[G3LD])(sm + 10240);
        unsigned short (*B1)[G3LD] = (unsigned short (*)[G3LD])(sm + 20480);
        unsigned short (*B2)[G3LD] = (unsigned short (*)[G3LD])(sm + 30720);

        const bool isK = id >= 512;
        const int lid = id & 511;
        const int bm = (lid & 31) * TM;   // token tile (M=4096)
        const int bn = (lid >> 5) * TN;   // output tile (N=2048)
        const float* A = x;
        const float* W = isK ? Wk : Wq;
        const float* bias = isK ? bk : bq;

        f32x4 acc[4][4];
        #pragma unroll
        for (int i = 0; i < 4; ++i)
            #pragma unroll
            for (int j = 0; j < 4; ++j)
                acc[i][j] = (f32x4){0.f, 0.f, 0.f, 0.f};

        for (int kt = 0; kt < K; kt += 32) {
            __syncthreads();
            {
                const float* Ag = A + (size_t)(bm + lrow) * K + kt + lcol;
                const float* Wg = W + (size_t)(bn + lrow) * K + kt + lcol;
                float4 v0, v1; su4 h0, l0, h1, l1;
                v0 = *(const float4*)(Ag + 0);  v1 = *(const float4*)(Ag + 4);
                split2_4(v0, h0, l0); split2_4(v1, h1, l1);
                *(su8*)&A1[lrow][lcol + 0] = cat44(h0, h1);
                *(su8*)&A2[lrow][lcol + 0] = cat44(l0, l1);
                v0 = *(const float4*)(Ag + 8);  v1 = *(const float4*)(Ag + 12);
                split2_4(v0, h0, l0); split2_4(v1, h1, l1);
                *(su8*)&A1[lrow][lcol + 8] = cat44(h0, h1);
                *(su8*)&A2[lrow][lcol + 8] = cat44(l0, l1);
                v0 = *(const float4*)(Wg + 0);  v1 = *(const float4*)(Wg + 4);
                split2_4(v0, h0, l0); split2_4(v1, h1, l1);
                *(su8*)&B1[lrow][lcol + 0] = cat44(h0, h1);
                *(su8*)&B2[lrow][lcol + 0] = cat44(l0, l1);
                v0 = *(const float4*)(Wg + 8);  v1 = *(const float4*)(Wg + 12);
                split2_4(v0, h0, l0); split2_4(v1, h1, l1);
                *(su8*)&B1[lrow][lcol + 8] = cat44(h0, h1);
                *(su8*)&B2[lrow][lcol + 8] = cat44(l0, l1);
            }
            __syncthreads();

            su8 a1[4], a2[4], b1[4], b2[4];
            #pragma unroll
            for (int f = 0; f < 4; ++f) {
                const int fr = f * 16 + (lane & 15);
                const int fk = (lane >> 4) * 8;
                a1[f] = *(const su8*)&A1[wm * 64 + fr][fk];
                a2[f] = *(const su8*)&A2[wm * 64 + fr][fk];
                b1[f] = *(const su8*)&B1[wn * 64 + fr][fk];
                b2[f] = *(const su8*)&B2[wn * 64 + fr][fk];
            }
            #pragma unroll
            for (int fi = 0; fi < 4; ++fi)
                #pragma unroll
                for (int fj = 0; fj < 4; ++fj) {
                    asm volatile("v_mfma_f32_16x16x32_bf16 %0, %1, %2, %0"
                                 : "+v"(acc[fi][fj]) : "v"(a1[fi]), "v"(b2[fj]));
                    asm volatile("v_mfma_f32_16x16x32_bf16 %0, %1, %2, %0"
                                 : "+v"(acc[fi][fj]) : "v"(a2[fi]), "v"(b1[fj]));
                    asm volatile("v_mfma_f32_16x16x32_bf16 %0, %1, %2, %0"
                                 : "+v"(acc[fi][fj]) : "v"(a1[fi]), "v"(b1[fj]));
                }
        }

        asm volatile("s_nop 7\n\ts_nop 7" ::: "memory");

        if (!isK) {
            // ---- Q epilogue: fp32 C (round-12 verified, verbatim) ----
            #pragma unroll
            for (int fj = 0; fj < 4; ++fj) {
                const int col = bn + wn * 64 + fj * 16 + (lane & 15);
                const float bvv = bias[col];
                #pragma unroll
                for (int fi = 0; fi < 4; ++fi) {
                    const int r0 = bm + wm * 64 + fi * 16 + (lane >> 4) * 4;
                    #pragma unroll
                    for (int j = 0; j < 4; ++j)
                        Qb[(size_t)(r0 + j) * DD + col] = acc[fi][fj][j] + bvv;
                }
            }
        } else {
            // ---- K epilogue: 3 bf16 split planes (round-12 verified) ----
            #pragma unroll
            for (int fj = 0; fj < 4; ++fj) {
                const int col = bn + wn * 64 + fj * 16 + (lane & 15);
                const int h = col >> 7, d = col & (DKK - 1);
                const float bvv = bias[col];
                #pragma unroll
                for (int fi = 0; fi < 4; ++fi) {
                    const int r0 = bm + wm * 64 + fi * 16 + (lane >> 4) * 4;
                    #pragma unroll
                    for (int j = 0; j < 4; ++j) {
                        const int tok = r0 + j;
                        const float val = acc[fi][fj][j] + bvv;
                        const size_t o = ((size_t)((tok >> 10) * HH + h) * SS
                                          + (tok & (SS - 1))) * DKK + d;
                        unsigned short s1 = f2bf(val);
                        float r = val - bf2f(s1);
                        unsigned short s2 = f2bf(r);
                        float r2 = r - bf2f(s2);
                        Ks[0 * KPLANE + o] = s1;
                        Ks[1 * KPLANE + o] = s2;
                        Ks[2 * KPLANE + o] = f2bf(r2);
                    }
                }
            }
        }
    } else {
        // ================= V zone: 1-pass bf16, transposed out ============
        unsigned short (*Ab)[G3LD] = (unsigned short (*)[G3LD])(sm);
        unsigned short (*Bb)[G3LD] = (unsigned short (*)[G3LD])(sm + 10240);

        const int lid = id - 1024;
        const int bm = (lid & 15) * TM;   // vdim tile (M=2048)
        const int bn = (lid >> 4) * TN;   // token tile (N=4096)
        const float* A = Wv;
        const float* W = x;
        const int N = MROWS;

        f32x4 acc[4][4];
        #pragma unroll
        for (int i = 0; i < 4; ++i)
            #pragma unroll
            for (int j = 0; j < 4; ++j)
                acc[i][j] = (f32x4){0.f, 0.f, 0.f, 0.f};

        for (int kt = 0; kt < K; kt += 32) {
            __syncthreads();
            {
                const float* Ag = A + (size_t)(bm + lrow) * K + kt + lcol;
                const float* Wg = W + (size_t)(bn + lrow) * K + kt + lcol;
                float4 a0 = *(const float4*)(Ag + 0);
                float4 a1 = *(const float4*)(Ag + 4);
                float4 a2 = *(const float4*)(Ag + 8);
                float4 a3 = *(const float4*)(Ag + 12);
                *(su8*)&Ab[lrow][lcol + 0] = pack8(a0, a1);
                *(su8*)&Ab[lrow][lcol + 8] = pack8(a2, a3);
                float4 b0 = *(const float4*)(Wg + 0);
                float4 b1 = *(const float4*)(Wg + 4);
                float4 b2 = *(const float4*)(Wg + 8);
                float4 b3 = *(const float4*)(Wg + 12);
                *(su8*)&Bb[lrow][lcol + 0] = pack8(b0, b1);
                *(su8*)&Bb[lrow][lcol + 8] = pack8(b2, b3);
            }
            __syncthreads();

            su8 af[4], bf[4];
            #pragma unroll
            for (int f = 0; f < 4; ++f) {
                af[f] = *(const su8*)&Ab[wm * 64 + f * 16 + (lane & 15)][(lane >> 4) * 8];
                bf[f] = *(const su8*)&Bb[wn * 64 + f * 16 + (lane & 15)][(lane >> 4) * 8];
            }
            #pragma unroll
            for (int fi = 0; fi < 4; ++fi)
                #pragma unroll
                for (int fj = 0; fj < 4; ++fj)
                    asm volatile("v_mfma_f32_16x16x32_bf16 %0, %1, %2, %0"
                                 : "+v"(acc[fi][fj])
                                 : "v"(af[fi]), "v"(bf[fj]));
        }

        asm volatile("s_nop 7\n\ts_nop 7" ::: "memory");

        #pragma unroll
        for (int fj = 0; fj < 4; ++fj) {
            const int col = bn + wn * 64 + fj * 16 + (lane & 15);
            #pragma unroll
            for (int fi = 0; fi < 4; ++fi) {
                const int r0 = bm + wm * 64 + fi * 16 + (lane >> 4) * 4;
                #pragma unroll
                for (int j = 0; j < 4; ++j) {
                    float v = acc[fi][fj][j] + bv[r0 + j];
                    Vt[(size_t)(r0 + j) * N + col] = f2bf(v);
                }
            }
        }
    }
}

// ---------------------------------------------------------------------------
// GEMM bf16-MFMA (round-6 verified, verbatim): fp32 in/out. Used for O-proj.
// ---------------------------------------------------------------------------
#define GLDA 40

__global__ __launch_bounds__(256) void gemm_nt_bf16(
    const float* __restrict__ A, const float* __restrict__ W,
    const float* __restrict__ bias, float* __restrict__ C,
    int M, int N, int K)
{
    __shared__ unsigned short Ab[128][GLDA];
    __shared__ unsigned short Bb[128][GLDA];

    const int tid = threadIdx.x;
    const int bm = blockIdx.x * 128;
    const int bn = blockIdx.y * 128;
    const int wm = (tid >> 6) & 1;
    const int wn = tid >> 7;
    const int lane = tid & 63;
    const int lrow = tid >> 1;
    const int lcol = (tid & 1) * 16;

    f32x4 acc[4][4];
    #pragma unroll
    for (int i = 0; i < 4; ++i)
        #pragma unroll
        for (int j = 0; j < 4; ++j)
            acc[i][j] = (f32x4){0.f, 0.f, 0.f, 0.f};

    for (int kt = 0; kt < K; kt += 32) {
        __syncthreads();
        {
            const float* Ag = A + (size_t)(bm + lrow) * K + kt + lcol;
            const float* Wg = W + (size_t)(bn + lrow) * K + kt + lcol;
            float4 a0 = *(const float4*)(Ag + 0);
            float4 a1 = *(const float4*)(Ag + 4);
            float4 a2 = *(const float4*)(Ag + 8);
            float4 a3 = *(const float4*)(Ag + 12);
            *(su8*)&Ab[lrow][lcol + 0] = pack8(a0, a1);
            *(su8*)&Ab[lrow][lcol + 8] = pack8(a2, a3);
            float4 b0 = *(const float4*)(Wg + 0);
            float4 b1 = *(const float4*)(Wg + 4);
            float4 b2 = *(const float4*)(Wg + 8);
            float4 b3 = *(const float4*)(Wg + 12);
            *(su8*)&Bb[lrow][lcol + 0] = pack8(b0, b1);
            *(su8*)&Bb[lrow][lcol + 8] = pack8(b2, b3);
        }
        __syncthreads();

        su8 af[4], bf[4];
        #pragma unroll
        for (int f = 0; f < 4; ++f) {
            af[f] = *(const su8*)&Ab[wm * 64 + f * 16 + (lane & 15)][(lane >> 4) * 8];
            bf[f] = *(const su8*)&Bb[wn * 64 + f * 16 + (lane & 15)][(lane >> 4) * 8];
        }
        #pragma unroll
        for (int fi = 0; fi < 4; ++fi)
            #pragma unroll
            for (int fj = 0; fj < 4; ++fj)
                asm volatile("v_mfma_f32_16x16x32_bf16 %0, %1, %2, %0"
                             : "+v"(acc[fi][fj])
                             : "v"(af[fi]), "v"(bf[fj]));
    }

    asm volatile("s_nop 7\n\ts_nop 7" ::: "memory");

    #pragma unroll
    for (int fj = 0; fj < 4; ++fj) {
        const int col = bn + wn * 64 + fj * 16 + (lane & 15);
        const float bv = bias[col];
        #pragma unroll
        for (int fi = 0; fi < 4; ++fi) {
            const int r0 = bm + wm * 64 + fi * 16 + (lane >> 4) * 4;
            #pragma unroll
            for (int j = 0; j < 4; ++j)
                C[(size_t)(r0 + j) * N + col] = acc[fi][fj][j] + bv;
        }
    }
}

// ---------------------------------------------------------------------------
// Fused attn — round-13 anchor, verbatim (attn ~525 us).
// ---------------------------------------------------------------------------
#define ATT_LDS 65280

__global__ __launch_bounds__(512) void attn_topk_fused(
    const float* __restrict__ Qb, const unsigned short* __restrict__ Ks,
    const unsigned short* __restrict__ Vt, float* __restrict__ attn_out,
    float* __restrict__ CTX)
{
    __shared__ __align__(16) char smem[ATT_LDS];
    unsigned short* q_s = (unsigned short*)smem;                   // [3][16][136]
    unsigned short* k_s = (unsigned short*)(smem + 13056);         // [3][64][136]
    float*          red = (float*)smem;                            // [4][16][16]
    unsigned short* wt  = (unsigned short*)(smem + 13056);         // [16][1032]
    unsigned short* vt  = (unsigned short*)(smem + 13056 + 33024); // [128][72]

    const int tid = threadIdx.x;
    const int wv = tid >> 6, lane = tid & 63;
    const int fg = lane >> 4, fc = lane & 15;

    // XCD-chunked bijective remap: 4096 = 8 XCDs x 512
    const int gg = (blockIdx.x & 7) * 512 + ((int)blockIdx.x >> 3);
    const int bh = gg >> 6, qb = gg & 63;
    const int b = bh >> 4, h = bh & 15;
    const int q0 = qb * 16;

    const float* Qg = Qb + (size_t)(b * SS + q0) * DD + h * DKK;
    const unsigned short* Ksg = Ks + (size_t)bh * SS * DKK;
    const unsigned short* Vtg = Vt + (size_t)(h * DKK) * MROWS + b * SS;
    float* aob = attn_out + (size_t)(bh * SS + q0) * SS;

    // ---- issue K tile-0 prefetch before Q staging (overlaps) ----
    su8 rk[6];
    #pragma unroll
    for (int pu = 0; pu < 6; ++pu) {
        const int p = pu >> 1;
        const int rem = tid + 512 * (pu & 1);
        const int row = rem >> 4, c8 = rem & 15;
        rk[pu] = *(const su8*)(Ksg + p * KPLANE +
                               (size_t)row * DKK + c8 * 8);
    }

    // ---- stage Q splits (once): 512 units = 16 rows x 32 c4 ----
    {
        int row = tid >> 5, c4 = tid & 31;
        float4 v = *(const float4*)(Qg + (size_t)row * DD + c4 * 4);
        int off = row * 136 + c4 * 4;
        su4 p1, p2, p3; split4(v, p1, p2, p3);
        *(su4*)&q_s[off] = p1;
        *(su4*)&q_s[2176 + off] = p2;
        *(su4*)&q_s[4352 + off] = p3;
    }
    __syncthreads();

    // ---- persistent A-frags: af[split][ktile-of-my-dhalf] ----
    const int kt0 = (wv >> 2) * 2;   // ktile base: 0 (d 0..63) or 2 (d 64..127)
    su8 af[3][2];
    #pragma unroll
    for (int p = 0; p < 3; ++p)
        #pragma unroll
        for (int kk = 0; kk < 2; ++kk)
            af[p][kk] = *(const su8*)&q_s[p * 2176 + fc * 136 +
                            ((kt0 + kk) * 4 + fg) * 8];

    // ---- scores over 16 key-tiles of 64 (prefetched pipeline) ----
    unsigned uv[2][16];
    for (int t = 0; t < 16; ++t) {
        // write prefetched tile t (k_s reads of t-1 done before barrier-2(t-1))
        #pragma unroll
        for (int pu = 0; pu < 6; ++pu) {
            const int p = pu >> 1;
            const int rem = tid + 512 * (pu & 1);
            const int row = rem >> 4, c8 = rem & 15;
            *(su8*)&k_s[p * 8704 + row * 136 + c8 * 8] = rk[pu];
        }
        // issue loads for tile t+1 (fly during MFMA + barriers)
        if (t < 15) {
            #pragma unroll
            for (int pu = 0; pu < 6; ++pu) {
                const int p = pu >> 1;
                const int rem = tid + 512 * (pu & 1);
                const int row = rem >> 4, c8 = rem & 15;
                rk[pu] = *(const su8*)(Ksg + p * KPLANE +
                            (size_t)((t + 1) * 64 + row) * DKK + c8 * 8);
            }
        }
        __syncthreads();   // barrier-1: k_s tile t visible

        const int krow = (wv & 3) * 16 + fc;
        su8 bf[3][2];
        #pragma unroll
        for (int p = 0; p < 3; ++p)
            #pragma unroll
            for (int kk = 0; kk < 2; ++kk)
                bf[p][kk] = *(const su8*)&k_s[p * 8704 + krow * 136 +
                                ((kt0 + kk) * 4 + fg) * 8];

        f32x4 acc = {0.f, 0.f, 0.f, 0.f};
        // passes small->large: (q3,k1),(q1,k3),(q2,k2),(q2,k1),(q1,k2),(q1,k1)
        constexpr int PI[6] = {2, 0, 1, 1, 0, 0};
        constexpr int PJ[6] = {0, 2, 1, 0, 1, 0};
        #pragma unroll
        for (int p = 0; p < 6; ++p)
            #pragma unroll
            for (int kk = 0; kk < 2; ++kk)
                asm volatile("v_mfma_f32_16x16x32_bf16 %0, %1, %2, %0"
                             : "+v"(acc) : "v"(af[PI[p]][kk]), "v"(bf[PJ[p]][kk]));
        asm volatile("s_nop 7\n\ts_nop 7" ::: "memory");

        if (kt0 == 2) {
            #pragma unroll
            for (int j = 0; j < 4; ++j)
                red[(wv & 3) * 256 + (4 * fg + j) * 16 + fc] = acc[j];
        }
        __syncthreads();   // barrier-2: red visible; k_s reads done
        if (kt0 == 0) {
            #pragma unroll
            for (int j = 0; j < 4; ++j) {
                float s = (acc[j] + red[(wv & 3) * 256 + (4 * fg + j) * 16 + fc]) * SCALE;
                aob[(size_t)(4 * fg + j) * SS + t * 64 + (wv & 3) * 16 + fc] = s;
            }
        }
    }
    __syncthreads();  // all scores visible within block

    // ---- selection + softmax params (verified ballot bit-descent), 2 rows ----
    #pragma unroll
    for (int rr = 0; rr < 2; ++rr) {
        const float* aor = aob + (size_t)(2 * wv + rr) * SS;
        #pragma unroll
        for (int t = 0; t < 16; ++t)
            uv[rr][t] = f2u_ord(aor[t * 64 + lane]);
    }
    unsigned pref[2]; int ecnt[2]; float mrow[2], invz[2], tvexp[2];
    #pragma unroll
    for (int rr = 0; rr < 2; ++rr) {
        unsigned p = 0;
        for (int bit = 31; bit >= 0; --bit) {
            unsigned cand = p | (1u << bit);
            int cnt = 0;
            #pragma unroll
            for (int t = 0; t < 16; ++t)
                cnt += __popcll(__ballot(uv[rr][t] >= cand));
            if (cnt >= KKTOP) p = cand;
        }
        pref[rr] = p;
        int g = 0;
        #pragma unroll
        for (int t = 0; t < 16; ++t)
            g += __popcll(__ballot(uv[rr][t] > p));
        ecnt[rr] = KKTOP - g;

        unsigned um = 0;
        #pragma unroll
        for (int t = 0; t < 16; ++t) um = um > uv[rr][t] ? um : uv[rr][t];
        #pragma unroll
        for (int o = 32; o > 0; o >>= 1) {
            unsigned tv2 = __shfl_down(um, o);
            um = um > tv2 ? um : tv2;
        }
        um = __shfl(um, 0);
        const float m = u2f_ord(um);

        float se = 0.f;
        #pragma unroll
        for (int t = 0; t < 16; ++t)
            if (uv[rr][t] > p) se += expf(u2f_ord(uv[rr][t]) - m);
        #pragma unroll
        for (int o = 32; o > 0; o >>= 1) se += __shfl_down(se, o);
        se = __shfl(se, 0);

        mrow[rr] = m;
        tvexp[rr] = expf(u2f_ord(p) - m);
        invz[rr] = 1.0f / (se + (float)ecnt[rr] * tvexp[rr]);
    }

    // ---- weights: attn_out final + wt bf16 (ties in (t,lane) index order) ----
    #pragma unroll
    for (int rr = 0; rr < 2; ++rr) {
        float* aor = aob + (size_t)(2 * wv + rr) * SS;
        unsigned short* wr = wt + (2 * wv + rr) * 1032;
        int tiesbefore = 0;
        #pragma unroll
        for (int t = 0; t < 16; ++t) {
            const unsigned u = uv[rr][t];
            const bool eq = (u == pref[rr]);
            unsigned long long mask = __ballot(eq);
            float w;
            if (u > pref[rr]) {
                w = expf(u2f_ord(u) - mrow[rr]) * invz[rr];
            } else if (eq) {
                int rank = tiesbefore + __popcll(mask & ((1ull << lane) - 1ull));
                w = (rank < ecnt[rr]) ? tvexp[rr] * invz[rr] : 0.f;
            } else {
                w = 0.f;
            }
            aor[t * 64 + lane] = w;
            wr[t * 64 + lane] = f2bf(w);
            tiesbefore += __popcll(mask);
        }
    }

    // ---- PV: ctx[16][128] = W[16][1024] @ V[1024][128], prefetched ----
    f32x4 pacc = {0.f, 0.f, 0.f, 0.f};
    const int pvd = wv * 16 + fc;        // this lane's d column
    su8 rv[2];
    #pragma unroll
    for (int u = 0; u < 2; ++u) {
        int rem = tid + 512 * u;
        int d = rem >> 3, kc = rem & 7;
        rv[u] = *(const su8*)(Vtg + (size_t)d * MROWS + kc * 8);
    }
    for (int t = 0; t < 16; ++t) {
        __syncthreads();   // wt complete (t=0) / prev vt MFMA reads done
        #pragma unroll
        for (int u = 0; u < 2; ++u) {
            int rem = tid + 512 * u;
            int d = rem >> 3, kc = rem & 7;
            *(su8*)&vt[d * 72 + kc * 8] = rv[u];
        }
        if (t < 15) {
            #pragma unroll
            for (int u = 0; u < 2; ++u) {
                int rem = tid + 512 * u;
                int d = rem >> 3, kc = rem & 7;
                rv[u] = *(const su8*)(Vtg + (size_t)d * MROWS +
                                      (t + 1) * 64 + kc * 8);
            }
        }
        __syncthreads();
        #pragma unroll
        for (int kk = 0; kk < 2; ++kk) {
            su8 aw = *(const su8*)&wt[fc * 1032 + t * 64 + (kk * 4 + fg) * 8];
            su8 bv2 = *(const su8*)&vt[pvd * 72 + (kk * 4 + fg) * 8];
            asm volatile("v_mfma_f32_16x16x32_bf16 %0, %1, %2, %0"
                         : "+v"(pacc) : "v"(aw), "v"(bv2));
        }
    }
    asm volatile("s_nop 7\n\ts_nop 7" ::: "memory");

    #pragma unroll
    for (int j = 0; j < 4; ++j)
        CTX[(size_t)(b * SS + q0 + 4 * fg + j) * DD + h * DKK + pvd] = pacc[j];
}

// ---------------------------------------------------------------------------
extern "C" void kernel_launch(void* const* d_in, const int* in_sizes, int n_in,
                              void* d_out, int out_size, void* d_ws, size_t ws_size,
                              hipStream_t stream)
{
    const float* x  = (const float*)d_in[0];
    const float* Wq = (const float*)d_in[1];
    const float* bq = (const float*)d_in[2];
    const float* Wk = (const float*)d_in[3];
    const float* bk = (const float*)d_in[4];
    const float* Wv = (const float*)d_in[5];
    const float* bv = (const float*)d_in[6];
    const float* Wo = (const float*)d_in[7];
    const float* bo = (const float*)d_in[8];

    float* out      = (float*)d_out;                       // [4,1024,2048]
    float* attn_out = (float*)d_out + (size_t)MROWS * DD;  // [4,16,1024,1024]

    float* ws = (float*)d_ws;
    const size_t PLANE = (size_t)MROWS * DD;   // 8,388,608
    // ws carve (134.2 MB, identical to round-9..18):
    float* Qb = ws;
    unsigned short* Ksp = (unsigned short*)(ws + PLANE);
    float* CTX = ws + PLANE + PLANE * 3 / 2;
    unsigned short* Vtp = (unsigned short*)(ws + PLANE + PLANE * 3 / 2 + PLANE);

    // fused Q/K/V projections: one 1536-block dispatch (zones 512/512/512)
    qkv_proj<<<dim3(1536), 256, 0, stream>>>(
        x, Wq, bq, Wk, bk, Wv, bv, Qb, Ksp, Vtp);

    attn_topk_fused<<<dim3(BB * HH * (SS / 16)), 512, 0, stream>>>(
        Qb, Ksp, Vtp, attn_out, CTX);

    gemm_nt_bf16<<<dim3(MROWS / TM, DD / TN), 256, 0, stream>>>(
        CTX, Wo, bo, out, MROWS, DD, DD);
}

// Round 20
// 911.156 us; speedup vs baseline: 1.3441x; 1.0029x over previous
//
#include <hip/hip_runtime.h>
#include <math.h>

// Problem constants
#define BB 4
#define SS 1024
#define DD 2048
#define HH 16
#define DKK 128
#define KKTOP 307           // int(1024 * 0.3)
#define MROWS (BB * SS)     // 4096
#define KPLANE ((size_t)MROWS * DD)   // elements per K-split plane (8,388,608)
static __device__ __constant__ float SCALE = 0.08838834764831845f; // 1/sqrt(128)

typedef float f32x4 __attribute__((ext_vector_type(4)));
typedef unsigned short su4 __attribute__((ext_vector_type(4)));
typedef unsigned short su8 __attribute__((ext_vector_type(8)));

__device__ __forceinline__ unsigned short f2bf(float x) {   // RNE
    unsigned u = __float_as_uint(x);
    u += 0x7fffu + ((u >> 16) & 1u);
    return (unsigned short)(u >> 16);
}
__device__ __forceinline__ float bf2f(unsigned short b) {
    return __uint_as_float((unsigned)b << 16);
}
__device__ __forceinline__ unsigned f2u_ord(float f) {
    unsigned x = __float_as_uint(f);
    return (x & 0x80000000u) ? ~x : (x | 0x80000000u);
}
__device__ __forceinline__ float u2f_ord(unsigned u) {
    return __uint_as_float((u & 0x80000000u) ? (u & 0x7fffffffu) : ~u);
}
// 3-way bf16 split of fp32 (captures ~24 mantissa bits)
__device__ __forceinline__ void split4(float4 v, su4& a, su4& b, su4& c) {
    float x[4] = {v.x, v.y, v.z, v.w};
    #pragma unroll
    for (int i = 0; i < 4; ++i) {
        unsigned short b1 = f2bf(x[i]);
        float r = x[i] - bf2f(b1);
        unsigned short b2 = f2bf(r);
        float r2 = r - bf2f(b2);
        a[i] = b1; b[i] = b2; c[i] = f2bf(r2);
    }
}
// 2-way bf16 split of fp32 (residual <= 2^-9 |x|)
__device__ __forceinline__ void split2_4(float4 v, su4& a, su4& b) {
    float x[4] = {v.x, v.y, v.z, v.w};
    #pragma unroll
    for (int i = 0; i < 4; ++i) {
        unsigned short b1 = f2bf(x[i]);
        float r = x[i] - bf2f(b1);
        a[i] = b1; b[i] = f2bf(r);
    }
}
__device__ __forceinline__ su8 cat44(su4 a, su4 b) {
    su8 r;
    r[0] = a[0]; r[1] = a[1]; r[2] = a[2]; r[3] = a[3];
    r[4] = b[0]; r[5] = b[1]; r[6] = b[2]; r[7] = b[3];
    return r;
}
__device__ __forceinline__ su8 pack8(float4 x, float4 y) {
    su8 r;
    r[0] = f2bf(x.x); r[1] = f2bf(x.y); r[2] = f2bf(x.z); r[3] = f2bf(x.w);
    r[4] = f2bf(y.x); r[5] = f2bf(y.y); r[6] = f2bf(y.z); r[7] = f2bf(y.w);
    return r;
}

#define TM 128
#define TN 128
#define G3LD 40

// ---------------------------------------------------------------------------
// Fused QKV projection (round-19 verified) + XCD-chunked zone remap:
// within each 512-block zone, lid = (raw&7)*64 + (raw>>3) gives each XCD a
// contiguous 64-tile chunk (2 bn-columns of W resident in its L2).
//   zone [0,512):    Q = x@Wq^T+bq, 3-pass split-bf16 core, fp32 out
//   zone [512,1024): K = x@Wk^T+bk, 3-pass core + 3-plane ksplit epilogue
//   zone [1024,1536): Vt = (Wv@x^T+bv[row]) bf16 out, 1-pass core
// ---------------------------------------------------------------------------
__global__ __launch_bounds__(256) void qkv_proj(
    const float* __restrict__ x,
    const float* __restrict__ Wq, const float* __restrict__ bq,
    const float* __restrict__ Wk, const float* __restrict__ bk,
    const float* __restrict__ Wv, const float* __restrict__ bv,
    float* __restrict__ Qb, unsigned short* __restrict__ Ks,
    unsigned short* __restrict__ Vt)
{
    __shared__ __align__(16) char sm[40960];

    const int tid = threadIdx.x;
    const int id = blockIdx.x;
    const int wm = (tid >> 6) & 1;
    const int wn = tid >> 7;
    const int lane = tid & 63;
    const int lrow = tid >> 1;
    const int lcol = (tid & 1) * 16;
    const int K = DD;

    if (id < 1024) {
        // ================= 3-pass zones: Q (id<512) / K =================
        unsigned short (*A1)[G3LD] = (unsigned short (*)[G3LD])(sm);
        unsigned short (*A2)[G3LD] = (unsigned short (*)[G3LD])(sm + 10240);
        unsigned short (*B1)[G3LD] = (unsigned short (*)[G3LD])(sm + 20480);
        unsigned short (*B2)[G3LD] = (unsigned short (*)[G3LD])(sm + 30720);

        const bool isK = id >= 512;
        const int zid = id & 511;
        const int lid = (zid & 7) * 64 + (zid >> 3);   // XCD-chunked remap
        const int bm = (lid & 31) * TM;   // token tile (M=4096)
        const int bn = (lid >> 5) * TN;   // output tile (N=2048)
        const float* A = x;
        const float* W = isK ? Wk : Wq;
        const float* bias = isK ? bk : bq;

        f32x4 acc[4][4];
        #pragma unroll
        for (int i = 0; i < 4; ++i)
            #pragma unroll
            for (int j = 0; j < 4; ++j)
                acc[i][j] = (f32x4){0.f, 0.f, 0.f, 0.f};

        for (int kt = 0; kt < K; kt += 32) {
            __syncthreads();
            {
                const float* Ag = A + (size_t)(bm + lrow) * K + kt + lcol;
                const float* Wg = W + (size_t)(bn + lrow) * K + kt + lcol;
                float4 v0, v1; su4 h0, l0, h1, l1;
                v0 = *(const float4*)(Ag + 0);  v1 = *(const float4*)(Ag + 4);
                split2_4(v0, h0, l0); split2_4(v1, h1, l1);
                *(su8*)&A1[lrow][lcol + 0] = cat44(h0, h1);
                *(su8*)&A2[lrow][lcol + 0] = cat44(l0, l1);
                v0 = *(const float4*)(Ag + 8);  v1 = *(const float4*)(Ag + 12);
                split2_4(v0, h0, l0); split2_4(v1, h1, l1);
                *(su8*)&A1[lrow][lcol + 8] = cat44(h0, h1);
                *(su8*)&A2[lrow][lcol + 8] = cat44(l0, l1);
                v0 = *(const float4*)(Wg + 0);  v1 = *(const float4*)(Wg + 4);
                split2_4(v0, h0, l0); split2_4(v1, h1, l1);
                *(su8*)&B1[lrow][lcol + 0] = cat44(h0, h1);
                *(su8*)&B2[lrow][lcol + 0] = cat44(l0, l1);
                v0 = *(const float4*)(Wg + 8);  v1 = *(const float4*)(Wg + 12);
                split2_4(v0, h0, l0); split2_4(v1, h1, l1);
                *(su8*)&B1[lrow][lcol + 8] = cat44(h0, h1);
                *(su8*)&B2[lrow][lcol + 8] = cat44(l0, l1);
            }
            __syncthreads();

            su8 a1[4], a2[4], b1[4], b2[4];
            #pragma unroll
            for (int f = 0; f < 4; ++f) {
                const int fr = f * 16 + (lane & 15);
                const int fk = (lane >> 4) * 8;
                a1[f] = *(const su8*)&A1[wm * 64 + fr][fk];
                a2[f] = *(const su8*)&A2[wm * 64 + fr][fk];
                b1[f] = *(const su8*)&B1[wn * 64 + fr][fk];
                b2[f] = *(const su8*)&B2[wn * 64 + fr][fk];
            }
            #pragma unroll
            for (int fi = 0; fi < 4; ++fi)
                #pragma unroll
                for (int fj = 0; fj < 4; ++fj) {
                    asm volatile("v_mfma_f32_16x16x32_bf16 %0, %1, %2, %0"
                                 : "+v"(acc[fi][fj]) : "v"(a1[fi]), "v"(b2[fj]));
                    asm volatile("v_mfma_f32_16x16x32_bf16 %0, %1, %2, %0"
                                 : "+v"(acc[fi][fj]) : "v"(a2[fi]), "v"(b1[fj]));
                    asm volatile("v_mfma_f32_16x16x32_bf16 %0, %1, %2, %0"
                                 : "+v"(acc[fi][fj]) : "v"(a1[fi]), "v"(b1[fj]));
                }
        }

        asm volatile("s_nop 7\n\ts_nop 7" ::: "memory");

        if (!isK) {
            // ---- Q epilogue: fp32 C (round-12 verified, verbatim) ----
            #pragma unroll
            for (int fj = 0; fj < 4; ++fj) {
                const int col = bn + wn * 64 + fj * 16 + (lane & 15);
                const float bvv = bias[col];
                #pragma unroll
                for (int fi = 0; fi < 4; ++fi) {
                    const int r0 = bm + wm * 64 + fi * 16 + (lane >> 4) * 4;
                    #pragma unroll
                    for (int j = 0; j < 4; ++j)
                        Qb[(size_t)(r0 + j) * DD + col] = acc[fi][fj][j] + bvv;
                }
            }
        } else {
            // ---- K epilogue: 3 bf16 split planes (round-12 verified) ----
            #pragma unroll
            for (int fj = 0; fj < 4; ++fj) {
                const int col = bn + wn * 64 + fj * 16 + (lane & 15);
                const int h = col >> 7, d = col & (DKK - 1);
                const float bvv = bias[col];
                #pragma unroll
                for (int fi = 0; fi < 4; ++fi) {
                    const int r0 = bm + wm * 64 + fi * 16 + (lane >> 4) * 4;
                    #pragma unroll
                    for (int j = 0; j < 4; ++j) {
                        const int tok = r0 + j;
                        const float val = acc[fi][fj][j] + bvv;
                        const size_t o = ((size_t)((tok >> 10) * HH + h) * SS
                                          + (tok & (SS - 1))) * DKK + d;
                        unsigned short s1 = f2bf(val);
                        float r = val - bf2f(s1);
                        unsigned short s2 = f2bf(r);
                        float r2 = r - bf2f(s2);
                        Ks[0 * KPLANE + o] = s1;
                        Ks[1 * KPLANE + o] = s2;
                        Ks[2 * KPLANE + o] = f2bf(r2);
                    }
                }
            }
        }
    } else {
        // ================= V zone: 1-pass bf16, transposed out ============
        unsigned short (*Ab)[G3LD] = (unsigned short (*)[G3LD])(sm);
        unsigned short (*Bb)[G3LD] = (unsigned short (*)[G3LD])(sm + 10240);

        const int zid = id - 1024;
        const int lid = (zid & 7) * 64 + (zid >> 3);   // XCD-chunked remap
        const int bm = (lid & 15) * TM;   // vdim tile (M=2048)
        const int bn = (lid >> 4) * TN;   // token tile (N=4096)
        const float* A = Wv;
        const float* W = x;
        const int N = MROWS;

        f32x4 acc[4][4];
        #pragma unroll
        for (int i = 0; i < 4; ++i)
            #pragma unroll
            for (int j = 0; j < 4; ++j)
                acc[i][j] = (f32x4){0.f, 0.f, 0.f, 0.f};

        for (int kt = 0; kt < K; kt += 32) {
            __syncthreads();
            {
                const float* Ag = A + (size_t)(bm + lrow) * K + kt + lcol;
                const float* Wg = W + (size_t)(bn + lrow) * K + kt + lcol;
                float4 a0 = *(const float4*)(Ag + 0);
                float4 a1 = *(const float4*)(Ag + 4);
                float4 a2 = *(const float4*)(Ag + 8);
                float4 a3 = *(const float4*)(Ag + 12);
                *(su8*)&Ab[lrow][lcol + 0] = pack8(a0, a1);
                *(su8*)&Ab[lrow][lcol + 8] = pack8(a2, a3);
                float4 b0 = *(const float4*)(Wg + 0);
                float4 b1 = *(const float4*)(Wg + 4);
                float4 b2 = *(const float4*)(Wg + 8);
                float4 b3 = *(const float4*)(Wg + 12);
                *(su8*)&Bb[lrow][lcol + 0] = pack8(b0, b1);
                *(su8*)&Bb[lrow][lcol + 8] = pack8(b2, b3);
            }
            __syncthreads();

            su8 af[4], bf[4];
            #pragma unroll
            for (int f = 0; f < 4; ++f) {
                af[f] = *(const su8*)&Ab[wm * 64 + f * 16 + (lane & 15)][(lane >> 4) * 8];
                bf[f] = *(const su8*)&Bb[wn * 64 + f * 16 + (lane & 15)][(lane >> 4) * 8];
            }
            #pragma unroll
            for (int fi = 0; fi < 4; ++fi)
                #pragma unroll
                for (int fj = 0; fj < 4; ++fj)
                    asm volatile("v_mfma_f32_16x16x32_bf16 %0, %1, %2, %0"
                                 : "+v"(acc[fi][fj])
                                 : "v"(af[fi]), "v"(bf[fj]));
        }

        asm volatile("s_nop 7\n\ts_nop 7" ::: "memory");

        #pragma unroll
        for (int fj = 0; fj < 4; ++fj) {
            const int col = bn + wn * 64 + fj * 16 + (lane & 15);
            #pragma unroll
            for (int fi = 0; fi < 4; ++fi) {
                const int r0 = bm + wm * 64 + fi * 16 + (lane >> 4) * 4;
                #pragma unroll
                for (int j = 0; j < 4; ++j) {
                    float v = acc[fi][fj][j] + bv[r0 + j];
                    Vt[(size_t)(r0 + j) * N + col] = f2bf(v);
                }
            }
        }
    }
}

// ---------------------------------------------------------------------------
// GEMM bf16-MFMA O-projection (round-6 verified core) — 1D grid with
// XCD-chunked remap (512 = 8 XCDs x 64 contiguous tiles).
// ---------------------------------------------------------------------------
#define GLDA 40

__global__ __launch_bounds__(256) void gemm_nt_bf16(
    const float* __restrict__ A, const float* __restrict__ W,
    const float* __restrict__ bias, float* __restrict__ C,
    int M, int N, int K)
{
    __shared__ unsigned short Ab[128][GLDA];
    __shared__ unsigned short Bb[128][GLDA];

    const int tid = threadIdx.x;
    const int raw = blockIdx.x;
    const int lid = (raw & 7) * 64 + (raw >> 3);   // XCD-chunked remap
    const int bm = (lid & 31) * 128;
    const int bn = (lid >> 5) * 128;
    const int wm = (tid >> 6) & 1;
    const int wn = tid >> 7;
    const int lane = tid & 63;
    const int lrow = tid >> 1;
    const int lcol = (tid & 1) * 16;

    f32x4 acc[4][4];
    #pragma unroll
    for (int i = 0; i < 4; ++i)
        #pragma unroll
        for (int j = 0; j < 4; ++j)
            acc[i][j] = (f32x4){0.f, 0.f, 0.f, 0.f};

    for (int kt = 0; kt < K; kt += 32) {
        __syncthreads();
        {
            const float* Ag = A + (size_t)(bm + lrow) * K + kt + lcol;
            const float* Wg = W + (size_t)(bn + lrow) * K + kt + lcol;
            float4 a0 = *(const float4*)(Ag + 0);
            float4 a1 = *(const float4*)(Ag + 4);
            float4 a2 = *(const float4*)(Ag + 8);
            float4 a3 = *(const float4*)(Ag + 12);
            *(su8*)&Ab[lrow][lcol + 0] = pack8(a0, a1);
            *(su8*)&Ab[lrow][lcol + 8] = pack8(a2, a3);
            float4 b0 = *(const float4*)(Wg + 0);
            float4 b1 = *(const float4*)(Wg + 4);
            float4 b2 = *(const float4*)(Wg + 8);
            float4 b3 = *(const float4*)(Wg + 12);
            *(su8*)&Bb[lrow][lcol + 0] = pack8(b0, b1);
            *(su8*)&Bb[lrow][lcol + 8] = pack8(b2, b3);
        }
        __syncthreads();

        su8 af[4], bf[4];
        #pragma unroll
        for (int f = 0; f < 4; ++f) {
            af[f] = *(const su8*)&Ab[wm * 64 + f * 16 + (lane & 15)][(lane >> 4) * 8];
            bf[f] = *(const su8*)&Bb[wn * 64 + f * 16 + (lane & 15)][(lane >> 4) * 8];
        }
        #pragma unroll
        for (int fi = 0; fi < 4; ++fi)
            #pragma unroll
            for (int fj = 0; fj < 4; ++fj)
                asm volatile("v_mfma_f32_16x16x32_bf16 %0, %1, %2, %0"
                             : "+v"(acc[fi][fj])
                             : "v"(af[fi]), "v"(bf[fj]));
    }

    asm volatile("s_nop 7\n\ts_nop 7" ::: "memory");

    #pragma unroll
    for (int fj = 0; fj < 4; ++fj) {
        const int col = bn + wn * 64 + fj * 16 + (lane & 15);
        const float bv = bias[col];
        #pragma unroll
        for (int fi = 0; fi < 4; ++fi) {
            const int r0 = bm + wm * 64 + fi * 16 + (lane >> 4) * 4;
            #pragma unroll
            for (int j = 0; j < 4; ++j)
                C[(size_t)(r0 + j) * N + col] = acc[fi][fj][j] + bv;
        }
    }
}

// ---------------------------------------------------------------------------
// Fused attn — round-13 anchor, verbatim (attn ~525-530 us).
// ---------------------------------------------------------------------------
#define ATT_LDS 65280

__global__ __launch_bounds__(512) void attn_topk_fused(
    const float* __restrict__ Qb, const unsigned short* __restrict__ Ks,
    const unsigned short* __restrict__ Vt, float* __restrict__ attn_out,
    float* __restrict__ CTX)
{
    __shared__ __align__(16) char smem[ATT_LDS];
    unsigned short* q_s = (unsigned short*)smem;                   // [3][16][136]
    unsigned short* k_s = (unsigned short*)(smem + 13056);         // [3][64][136]
    float*          red = (float*)smem;                            // [4][16][16]
    unsigned short* wt  = (unsigned short*)(smem + 13056);         // [16][1032]
    unsigned short* vt  = (unsigned short*)(smem + 13056 + 33024); // [128][72]

    const int tid = threadIdx.x;
    const int wv = tid >> 6, lane = tid & 63;
    const int fg = lane >> 4, fc = lane & 15;

    // XCD-chunked bijective remap: 4096 = 8 XCDs x 512
    const int gg = (blockIdx.x & 7) * 512 + ((int)blockIdx.x >> 3);
    const int bh = gg >> 6, qb = gg & 63;
    const int b = bh >> 4, h = bh & 15;
    const int q0 = qb * 16;

    const float* Qg = Qb + (size_t)(b * SS + q0) * DD + h * DKK;
    const unsigned short* Ksg = Ks + (size_t)bh * SS * DKK;
    const unsigned short* Vtg = Vt + (size_t)(h * DKK) * MROWS + b * SS;
    float* aob = attn_out + (size_t)(bh * SS + q0) * SS;

    // ---- issue K tile-0 prefetch before Q staging (overlaps) ----
    su8 rk[6];
    #pragma unroll
    for (int pu = 0; pu < 6; ++pu) {
        const int p = pu >> 1;
        const int rem = tid + 512 * (pu & 1);
        const int row = rem >> 4, c8 = rem & 15;
        rk[pu] = *(const su8*)(Ksg + p * KPLANE +
                               (size_t)row * DKK + c8 * 8);
    }

    // ---- stage Q splits (once): 512 units = 16 rows x 32 c4 ----
    {
        int row = tid >> 5, c4 = tid & 31;
        float4 v = *(const float4*)(Qg + (size_t)row * DD + c4 * 4);
        int off = row * 136 + c4 * 4;
        su4 p1, p2, p3; split4(v, p1, p2, p3);
        *(su4*)&q_s[off] = p1;
        *(su4*)&q_s[2176 + off] = p2;
        *(su4*)&q_s[4352 + off] = p3;
    }
    __syncthreads();

    // ---- persistent A-frags: af[split][ktile-of-my-dhalf] ----
    const int kt0 = (wv >> 2) * 2;   // ktile base: 0 (d 0..63) or 2 (d 64..127)
    su8 af[3][2];
    #pragma unroll
    for (int p = 0; p < 3; ++p)
        #pragma unroll
        for (int kk = 0; kk < 2; ++kk)
            af[p][kk] = *(const su8*)&q_s[p * 2176 + fc * 136 +
                            ((kt0 + kk) * 4 + fg) * 8];

    // ---- scores over 16 key-tiles of 64 (prefetched pipeline) ----
    unsigned uv[2][16];
    for (int t = 0; t < 16; ++t) {
        // write prefetched tile t (k_s reads of t-1 done before barrier-2(t-1))
        #pragma unroll
        for (int pu = 0; pu < 6; ++pu) {
            const int p = pu >> 1;
            const int rem = tid + 512 * (pu & 1);
            const int row = rem >> 4, c8 = rem & 15;
            *(su8*)&k_s[p * 8704 + row * 136 + c8 * 8] = rk[pu];
        }
        // issue loads for tile t+1 (fly during MFMA + barriers)
        if (t < 15) {
            #pragma unroll
            for (int pu = 0; pu < 6; ++pu) {
                const int p = pu >> 1;
                const int rem = tid + 512 * (pu & 1);
                const int row = rem >> 4, c8 = rem & 15;
                rk[pu] = *(const su8*)(Ksg + p * KPLANE +
                            (size_t)((t + 1) * 64 + row) * DKK + c8 * 8);
            }
        }
        __syncthreads();   // barrier-1: k_s tile t visible

        const int krow = (wv & 3) * 16 + fc;
        su8 bf[3][2];
        #pragma unroll
        for (int p = 0; p < 3; ++p)
            #pragma unroll
            for (int kk = 0; kk < 2; ++kk)
                bf[p][kk] = *(const su8*)&k_s[p * 8704 + krow * 136 +
                                ((kt0 + kk) * 4 + fg) * 8];

        f32x4 acc = {0.f, 0.f, 0.f, 0.f};
        // passes small->large: (q3,k1),(q1,k3),(q2,k2),(q2,k1),(q1,k2),(q1,k1)
        constexpr int PI[6] = {2, 0, 1, 1, 0, 0};
        constexpr int PJ[6] = {0, 2, 1, 0, 1, 0};
        #pragma unroll
        for (int p = 0; p < 6; ++p)
            #pragma unroll
            for (int kk = 0; kk < 2; ++kk)
                asm volatile("v_mfma_f32_16x16x32_bf16 %0, %1, %2, %0"
                             : "+v"(acc) : "v"(af[PI[p]][kk]), "v"(bf[PJ[p]][kk]));
        asm volatile("s_nop 7\n\ts_nop 7" ::: "memory");

        if (kt0 == 2) {
            #pragma unroll
            for (int j = 0; j < 4; ++j)
                red[(wv & 3) * 256 + (4 * fg + j) * 16 + fc] = acc[j];
        }
        __syncthreads();   // barrier-2: red visible; k_s reads done
        if (kt0 == 0) {
            #pragma unroll
            for (int j = 0; j < 4; ++j) {
                float s = (acc[j] + red[(wv & 3) * 256 + (4 * fg + j) * 16 + fc]) * SCALE;
                aob[(size_t)(4 * fg + j) * SS + t * 64 + (wv & 3) * 16 + fc] = s;
            }
        }
    }
    __syncthreads();  // all scores visible within block

    // ---- selection + softmax params (verified ballot bit-descent), 2 rows ----
    #pragma unroll
    for (int rr = 0; rr < 2; ++rr) {
        const float* aor = aob + (size_t)(2 * wv + rr) * SS;
        #pragma unroll
        for (int t = 0; t < 16; ++t)
            uv[rr][t] = f2u_ord(aor[t * 64 + lane]);
    }
    unsigned pref[2]; int ecnt[2]; float mrow[2], invz[2], tvexp[2];
    #pragma unroll
    for (int rr = 0; rr < 2; ++rr) {
        unsigned p = 0;
        for (int bit = 31; bit >= 0; --bit) {
            unsigned cand = p | (1u << bit);
            int cnt = 0;
            #pragma unroll
            for (int t = 0; t < 16; ++t)
                cnt += __popcll(__ballot(uv[rr][t] >= cand));
            if (cnt >= KKTOP) p = cand;
        }
        pref[rr] = p;
        int g = 0;
        #pragma unroll
        for (int t = 0; t < 16; ++t)
            g += __popcll(__ballot(uv[rr][t] > p));
        ecnt[rr] = KKTOP - g;

        unsigned um = 0;
        #pragma unroll
        for (int t = 0; t < 16; ++t) um = um > uv[rr][t] ? um : uv[rr][t];
        #pragma unroll
        for (int o = 32; o > 0; o >>= 1) {
            unsigned tv2 = __shfl_down(um, o);
            um = um > tv2 ? um : tv2;
        }
        um = __shfl(um, 0);
        const float m = u2f_ord(um);

        float se = 0.f;
        #pragma unroll
        for (int t = 0; t < 16; ++t)
            if (uv[rr][t] > p) se += expf(u2f_ord(uv[rr][t]) - m);
        #pragma unroll
        for (int o = 32; o > 0; o >>= 1) se += __shfl_down(se, o);
        se = __shfl(se, 0);

        mrow[rr] = m;
        tvexp[rr] = expf(u2f_ord(p) - m);
        invz[rr] = 1.0f / (se + (float)ecnt[rr] * tvexp[rr]);
    }

    // ---- weights: attn_out final + wt bf16 (ties in (t,lane) index order) ----
    #pragma unroll
    for (int rr = 0; rr < 2; ++rr) {
        float* aor = aob + (size_t)(2 * wv + rr) * SS;
        unsigned short* wr = wt + (2 * wv + rr) * 1032;
        int tiesbefore = 0;
        #pragma unroll
        for (int t = 0; t < 16; ++t) {
            const unsigned u = uv[rr][t];
            const bool eq = (u == pref[rr]);
            unsigned long long mask = __ballot(eq);
            float w;
            if (u > pref[rr]) {
                w = expf(u2f_ord(u) - mrow[rr]) * invz[rr];
            } else if (eq) {
                int rank = tiesbefore + __popcll(mask & ((1ull << lane) - 1ull));
                w = (rank < ecnt[rr]) ? tvexp[rr] * invz[rr] : 0.f;
            } else {
                w = 0.f;
            }
            aor[t * 64 + lane] = w;
            wr[t * 64 + lane] = f2bf(w);
            tiesbefore += __popcll(mask);
        }
    }

    // ---- PV: ctx[16][128] = W[16][1024] @ V[1024][128], prefetched ----
    f32x4 pacc = {0.f, 0.f, 0.f, 0.f};
    const int pvd = wv * 16 + fc;        // this lane's d column
    su8 rv[2];
    #pragma unroll
    for (int u = 0; u < 2; ++u) {
        int rem = tid + 512 * u;
        int d = rem >> 3, kc = rem & 7;
        rv[u] = *(const su8*)(Vtg + (size_t)d * MROWS + kc * 8);
    }
    for (int t = 0; t < 16; ++t) {
        __syncthreads();   // wt complete (t=0) / prev vt MFMA reads done
        #pragma unroll
        for (int u = 0; u < 2; ++u) {
            int rem = tid + 512 * u;
            int d = rem >> 3, kc = rem & 7;
            *(su8*)&vt[d * 72 + kc * 8] = rv[u];
        }
        if (t < 15) {
            #pragma unroll
            for (int u = 0; u < 2; ++u) {
                int rem = tid + 512 * u;
                int d = rem >> 3, kc = rem & 7;
                rv[u] = *(const su8*)(Vtg + (size_t)d * MROWS +
                                      (t + 1) * 64 + kc * 8);
            }
        }
        __syncthreads();
        #pragma unroll
        for (int kk = 0; kk < 2; ++kk) {
            su8 aw = *(const su8*)&wt[fc * 1032 + t * 64 + (kk * 4 + fg) * 8];
            su8 bv2 = *(const su8*)&vt[pvd * 72 + (kk * 4 + fg) * 8];
            asm volatile("v_mfma_f32_16x16x32_bf16 %0, %1, %2, %0"
                         : "+v"(pacc) : "v"(aw), "v"(bv2));
        }
    }
    asm volatile("s_nop 7\n\ts_nop 7" ::: "memory");

    #pragma unroll
    for (int j = 0; j < 4; ++j)
        CTX[(size_t)(b * SS + q0 + 4 * fg + j) * DD + h * DKK + pvd] = pacc[j];
}

// ---------------------------------------------------------------------------
extern "C" void kernel_launch(void* const* d_in, const int* in_sizes, int n_in,
                              void* d_out, int out_size, void* d_ws, size_t ws_size,
                              hipStream_t stream)
{
    const float* x  = (const float*)d_in[0];
    const float* Wq = (const float*)d_in[1];
    const float* bq = (const float*)d_in[2];
    const float* Wk = (const float*)d_in[3];
    const float* bk = (const float*)d_in[4];
    const float* Wv = (const float*)d_in[5];
    const float* bv = (const float*)d_in[6];
    const float* Wo = (const float*)d_in[7];
    const float* bo = (const float*)d_in[8];

    float* out      = (float*)d_out;                       // [4,1024,2048]
    float* attn_out = (float*)d_out + (size_t)MROWS * DD;  // [4,16,1024,1024]

    float* ws = (float*)d_ws;
    const size_t PLANE = (size_t)MROWS * DD;   // 8,388,608
    // ws carve (134.2 MB, identical to round-9..19):
    float* Qb = ws;
    unsigned short* Ksp = (unsigned short*)(ws + PLANE);
    float* CTX = ws + PLANE + PLANE * 3 / 2;
    unsigned short* Vtp = (unsigned short*)(ws + PLANE + PLANE * 3 / 2 + PLANE);

    // fused Q/K/V projections: one 1536-block dispatch (zones 512/512/512)
    qkv_proj<<<dim3(1536), 256, 0, stream>>>(
        x, Wq, bq, Wk, bk, Wv, bv, Qb, Ksp, Vtp);

    attn_topk_fused<<<dim3(BB * HH * (SS / 16)), 512, 0, stream>>>(
        Qb, Ksp, Vtp, attn_out, CTX);

    gemm_nt_bf16<<<dim3(512), 256, 0, stream>>>(
        CTX, Wo, bo, out, MROWS, DD, DD);
}